// Round 9
// baseline (483.412 us; speedup 1.0000x reference)
//
#include <hip/hip_runtime.h>

#define EDGES 1000000
#define NODES 100000
#define ET 128   // edges per tile (4 waves x 32)
#define NB 32    // nodes per block (node_kernel); 100000 % 32 == 0
#define NBLK (NODES / NB)             // 3125
#define NBW ((NODES + 127) / 128)     // 782 wpos blocks

typedef short short8 __attribute__((ext_vector_type(8)));
typedef float floatx4 __attribute__((ext_vector_type(4)));
typedef unsigned int u32x2 __attribute__((ext_vector_type(2)));
typedef unsigned int u32x4 __attribute__((ext_vector_type(4)));

#define MFMA(a, b, c) __builtin_amdgcn_mfma_f32_16x16x32_bf16(a, b, c, 0, 0, 0)

// ws layout (bytes)
#define WS_WX1 0         // 32768: Wx1 bf16 frags
#define WS_WX2 32768     // 16384: Wx2 frags
#define WS_WP1 49152     // 16384: Wp1 frags
#define WS_MISC 65536    // 2048: biases etc (floats)
#define WS_OFF 68608     // off[100128] int = 400512 B (CSR offsets, padded)
#define WS_CNT 469504    // counts/cursor[100000] int = 400000 B (aliased)
#define WS_SREC 917504   // u32[EDGES] = 4 MB packed sorted records (lc<<17|r)
#define WS_POSW 8917504  // float4[NODES] = 1.6 MB {pos.xyz, w_pos} per node
#define WS_XB 10517504   // bf16[NODES][64] = 12.8 MB x pre-converted to bf16
// scan temporaries alias the srec region (they die before scatter writes srec):
#define WS_TMP WS_SREC                 // int[100352] inclusive per-block scans
#define WS_BSUM (WS_SREC + 401408)     // int[98] block sums

__device__ __forceinline__ unsigned short f2bf(float f) {
  union { float f; unsigned int u; } c;
  c.f = f;
  unsigned int u = c.u;
  u += 0x7fffu + ((u >> 16) & 1u);
  return (unsigned short)(u >> 16);
}

__device__ __forceinline__ unsigned int pack2bf(float lo, float hi) {
  return (unsigned int)f2bf(lo) | ((unsigned int)f2bf(hi) << 16);
}

// single-instruction RNE pack (same rounding as f2bf); no builtin on gfx950
__device__ __forceinline__ unsigned int cvtpk2bf(float lo, float hi) {
  unsigned int r;
  asm("v_cvt_pk_bf16_f32 %0, %1, %2" : "=v"(r) : "v"(lo), "v"(hi));
  return r;
}

// global -> LDS direct (16B/lane). LDS dest = uniform base + lane*16;
// global src is per-lane (guide m97/m104/m173).
__device__ __forceinline__ void gload16(const void* g, void* l) {
  __builtin_amdgcn_global_load_lds(
      (const __attribute__((address_space(1))) void*)g,
      (__attribute__((address_space(3))) void*)l, 16, 0, 0);
}

__device__ __forceinline__ float fast_silu(float v) {
#if __has_builtin(__builtin_amdgcn_exp2f) && __has_builtin(__builtin_amdgcn_rcpf)
  float e = __builtin_amdgcn_exp2f(-1.44269504088896340736f * v);
  return v * __builtin_amdgcn_rcpf(1.0f + e);
#else
  return v / (1.0f + __expf(-v));
#endif
}

// DPP cross-lane within 16-lane rows. MUST be called unconditionally in
// straight-line code (convergent ops).
template <int CTRL>
__device__ __forceinline__ int dpp_i(int v) {
  return __builtin_amdgcn_update_dpp(0, v, CTRL, 0xf, 0xf, true);
}
template <int CTRL>
__device__ __forceinline__ float dpp_f(float v) {
  return __builtin_bit_cast(float, dpp_i<CTRL>(__builtin_bit_cast(int, v)));
}

// Segmented inclusive prefix-sum across nn (16-lane row), segments = runs of
// equal sorted keys; masks m1..m8 from unconditional key equality at d=1,2,4,8.
__device__ __forceinline__ float segscan(float v, bool m1, bool m2, bool m4, bool m8) {
  float t;
  t = dpp_f<0x111>(v); v += m1 ? t : 0.f;
  t = dpp_f<0x112>(v); v += m2 ? t : 0.f;
  t = dpp_f<0x114>(v); v += m4 ? t : 0.f;
  t = dpp_f<0x118>(v); v += m8 ? t : 0.f;
  return v;
}

__device__ __forceinline__ void lds_add(float* p, float v) {
  __hip_atomic_fetch_add(p, v, __ATOMIC_RELAXED, __HIP_MEMORY_SCOPE_WORKGROUP);
}

// prep also zero-inits counts (wpos's folded hist runs after prep)
__global__ __launch_bounds__(256) void prep_kernel(
    const float* __restrict__ Wx1, const float* __restrict__ Wx2,
    const float* __restrict__ Wp1, const float* __restrict__ bx1,
    const float* __restrict__ bx2, const float* __restrict__ bp1,
    const float* __restrict__ Wp2, const float* __restrict__ bp2,
    unsigned char* __restrict__ ws) {
  const int t = blockIdx.x * 256 + threadIdx.x;
  const int nthr = gridDim.x * 256;

  int* counts = (int*)(ws + WS_CNT);
  for (int i = t; i < NODES; i += nthr) counts[i] = 0;

  for (int task = t; task < 2048; task += nthr) {  // Wx1[0:128][0:128]
    const int n = task & 127;
    const int kb = task >> 7;
    const int k0 = kb << 3;
    unsigned int d[4];
#pragma unroll
    for (int i = 0; i < 4; ++i)
      d[i] = pack2bf(Wx1[(k0 + 2 * i) * 128 + n], Wx1[(k0 + 2 * i + 1) * 128 + n]);
    const int lane = ((kb & 3) << 4) | (n & 15);
    const int frag = ((kb >> 2) << 3) | (n >> 4);
    *(uint4*)(ws + WS_WX1 + ((size_t)(frag * 64 + lane) << 4)) =
        make_uint4(d[0], d[1], d[2], d[3]);
  }
  for (int task = t; task < 1024; task += nthr) {  // Wx2[0:128][0:64]
    const int n = task & 63;
    const int kb = task >> 6;
    const int k0 = kb << 3;
    unsigned int d[4];
#pragma unroll
    for (int i = 0; i < 4; ++i)
      d[i] = pack2bf(Wx2[(k0 + 2 * i) * 64 + n], Wx2[(k0 + 2 * i + 1) * 64 + n]);
    const int lane = ((kb & 3) << 4) | (n & 15);
    const int frag = ((kb >> 2) << 2) | (n >> 4);
    *(uint4*)(ws + WS_WX2 + ((size_t)(frag * 64 + lane) << 4)) =
        make_uint4(d[0], d[1], d[2], d[3]);
  }
  for (int task = t; task < 1024; task += nthr) {  // Wp1[0:64][0:128]
    const int n = task & 127;
    const int kb = task >> 7;
    const int k0 = kb << 3;
    unsigned int d[4];
#pragma unroll
    for (int i = 0; i < 4; ++i)
      d[i] = pack2bf(Wp1[(k0 + 2 * i) * 128 + n], Wp1[(k0 + 2 * i + 1) * 128 + n]);
    const int lane = ((kb & 3) << 4) | (n & 15);
    const int frag = ((kb >> 2) << 3) | (n >> 4);
    *(uint4*)(ws + WS_WP1 + ((size_t)(frag * 64 + lane) << 4)) =
        make_uint4(d[0], d[1], d[2], d[3]);
  }
  float* misc = (float*)(ws + WS_MISC);
  for (int i = t; i < 128; i += nthr) misc[i] = bx1[i];
  for (int i = t; i < 64; i += nthr) misc[128 + i] = bx2[i];
  for (int i = t; i < 128; i += nthr) misc[192 + i] = bp1[i];
  for (int i = t; i < 128; i += nthr) misc[320 + i] = Wp2[i];
  if (t == 0) misc[448] = bp2[0];
  for (int i = t; i < 128; i += nthr) misc[456 + i] = Wx1[128 * 128 + i];
}

// ---- per-NODE phi_pos precompute + x -> bf16 + folded hist ----
__global__ __launch_bounds__(256) void wpos_kernel(
    const float* __restrict__ x, const float* __restrict__ pos,
    const int* __restrict__ ei, unsigned char* __restrict__ ws) {
  __shared__ float sX[128 * 68];  // 34816 B, stride 68 (16B-aligned, low conflict)

  const uint4* wp1f = (const uint4*)(ws + WS_WP1);
  const float* misc = (const float*)(ws + WS_MISC);
  float* posw = (float*)(ws + WS_POSW);
  unsigned char* xb = ws + WS_XB;
  int* counts = (int*)(ws + WS_CNT);

  const int tid = threadIdx.x;
  const int lane = tid & 63;
  const int wave = tid >> 6;
  const int q = lane >> 4;
  const int nn = lane & 15;
  const int B0 = blockIdx.x * 128;
  const int nvalid = (NODES - B0 < 128) ? (NODES - B0) : 128;

  // stage x[B0..B0+128) coalesced: 2048 float4s, 8 per thread
#pragma unroll
  for (int k = 0; k < 8; ++k) {
    const int fidx = tid + k * 256;  // float4 index
    const int row = fidx >> 4, c4 = fidx & 15;
    float4 v = make_float4(0.f, 0.f, 0.f, 0.f);
    if (row < nvalid) v = *(const float4*)(x + ((size_t)(B0 + row)) * 64 + c4 * 4);
    *(float4*)(sX + row * 68 + c4 * 4) = v;
  }
  __syncthreads();

  // xb bf16 copy: 4096 u32 outputs, 16 per thread, coalesced
#pragma unroll
  for (int k = 0; k < 16; ++k) {
    const int pidx = tid + k * 256;           // u32 index
    const int row = pidx >> 5, cp = pidx & 31;  // 32 u32 per 128B row
    if (B0 + row < NODES)
      *(unsigned int*)(xb + ((size_t)(B0 + row)) * 128 + cp * 4) =
          cvtpk2bf(sX[row * 68 + cp * 2], sX[row * 68 + cp * 2 + 1]);
  }

  // B-frags from LDS (invalid rows zero-filled; posw write is guarded)
  const int base = wave * 32;  // node-local base for this wave
  short8 bf[2][2];
#pragma unroll
  for (int m = 0; m < 2; ++m) {
    const int nl = base + m * 16 + nn;
#pragma unroll
    for (int kt = 0; kt < 2; ++kt) {
      const float4 a = *(const float4*)(sX + nl * 68 + kt * 32 + q * 8);
      const float4 b = *(const float4*)(sX + nl * 68 + kt * 32 + q * 8 + 4);
      u32x4 d;
      d[0] = cvtpk2bf(a.x, a.y);
      d[1] = cvtpk2bf(a.z, a.w);
      d[2] = cvtpk2bf(b.x, b.y);
      d[3] = cvtpk2bf(b.z, b.w);
      bf[m][kt] = __builtin_bit_cast(short8, d);
    }
  }

  const floatx4 fzero = {0.f, 0.f, 0.f, 0.f};
  floatx4 accp[2][8];
#pragma unroll
  for (int m = 0; m < 2; ++m)
#pragma unroll
    for (int j = 0; j < 8; ++j) accp[m][j] = fzero;
#pragma unroll 1
  for (int kt = 0; kt < 2; ++kt) {
#pragma unroll
    for (int jt = 0; jt < 8; ++jt) {
      const short8 a = __builtin_bit_cast(short8, wp1f[(kt * 8 + jt) * 64 + lane]);
      accp[0][jt] = MFMA(a, bf[0][kt], accp[0][jt]);
      accp[1][jt] = MFMA(a, bf[1][kt], accp[1][jt]);
    }
  }
#pragma unroll
  for (int m = 0; m < 2; ++m) {
    float s = 0.f;
#pragma unroll
    for (int jt = 0; jt < 8; ++jt) {
      const float4 bp = *(const float4*)(misc + 192 + jt * 16 + q * 4);
      const float4 wp = *(const float4*)(misc + 320 + jt * 16 + q * 4);
      s += fast_silu(accp[m][jt][0] + bp.x) * wp.x;
      s += fast_silu(accp[m][jt][1] + bp.y) * wp.y;
      s += fast_silu(accp[m][jt][2] + bp.z) * wp.z;
      s += fast_silu(accp[m][jt][3] + bp.w) * wp.w;
    }
    s += __shfl_xor(s, 16);
    s += __shfl_xor(s, 32);
    const int node = B0 + base + m * 16 + nn;
    if (q == 0 && node < NODES) {
      float4 o;
      o.x = pos[3 * node + 0];
      o.y = pos[3 * node + 1];
      o.z = pos[3 * node + 2];
      o.w = s + misc[448];
      *(float4*)(posw + 4 * (size_t)node) = o;
    }
  }

  // ---- folded hist (grid-stride; counts zeroed by prep)
  const int gsz = gridDim.x * 256;
  for (int t = blockIdx.x * 256 + tid; t < EDGES; t += gsz) {
    int c = __builtin_nontemporal_load(ei + EDGES + t);
    c = (c < 0) ? 0 : ((c >= NODES) ? NODES - 1 : c);
    atomicAdd(&counts[c], 1);
  }
}

#define SCB 98  // blocks of 1024: 98*1024 = 100352 >= NODES+128

__global__ __launch_bounds__(1024) void scan1_kernel(const int* __restrict__ counts,
                                                     int* __restrict__ tmp,
                                                     int* __restrict__ bsum) {
  __shared__ int part[1024];
  const int t = threadIdx.x;
  const int i = blockIdx.x * 1024 + t;
  int v = (i < NODES) ? counts[i] : 0;
  part[t] = v;
  __syncthreads();
  for (int d = 1; d < 1024; d <<= 1) {
    int u = 0;
    if (t >= d) u = part[t - d];
    __syncthreads();
    if (t >= d) part[t] += u;
    __syncthreads();
  }
  tmp[i] = part[t];  // inclusive scan within block
  if (t == 1023) bsum[blockIdx.x] = part[1023];
}

// scan2 merged in — each block re-scans the 98 block sums in LDS.
__global__ __launch_bounds__(1024) void scan3_kernel(const int* __restrict__ counts,
                                                     const int* __restrict__ tmp,
                                                     const int* __restrict__ bsum,
                                                     int* __restrict__ off,
                                                     int* __restrict__ cursor) {
  __shared__ int sb[128];
  const int t = threadIdx.x;
  if (t < 128) sb[t] = (t < SCB) ? bsum[t] : 0;
  __syncthreads();
  for (int d = 1; d < 128; d <<= 1) {
    int u = 0;
    if (t >= d && t < 128) u = sb[t - d];
    __syncthreads();
    if (t >= d && t < 128) sb[t] += u;
    __syncthreads();
  }
  const int bx = (blockIdx.x == 0) ? 0 : sb[blockIdx.x - 1];  // exclusive
  const int i = blockIdx.x * 1024 + t;
  if (i < NODES) {
    const int cn = counts[i];  // read before cursor write (aliased with counts)
    const int o = bx + tmp[i] - cn;
    off[i] = o;
    cursor[i] = o;
  } else if (i < NODES + 128) {
    off[i] = EDGES;
  }
}

// packed record — lc = c & 31 (NB=32; block base is (c>>5)*32), r < 2^17.
__global__ __launch_bounds__(256) void scatter_kernel(const int* __restrict__ ei,
                                                      int* __restrict__ cursor,
                                                      unsigned int* __restrict__ srec) {
  const int t = blockIdx.x * 256 + threadIdx.x;
  if (t < EDGES) {
    int r = __builtin_nontemporal_load(ei + t);
    int c = __builtin_nontemporal_load(ei + EDGES + t);
    r = (r < 0) ? 0 : ((r >= NODES) ? NODES - 1 : r);
    c = (c < 0) ? 0 : ((c >= NODES) ? NODES - 1 : c);
    const int p = atomicAdd(&cursor[c], 1);
    __builtin_nontemporal_store(((unsigned)(c & 31) << 17) | (unsigned)r, srec + p);
  }
}

// ---- main: node-centric, zero global atomics, zero in-loop barriers ----
// R18 = R17 with occupancy pushed 3 -> 4 blocks/CU. Binding limits at R17:
// regs 160/wave (VGPR 80 + AGPR 80) and LDS 49152 — both gave 12 waves/CU.
// (a) sH 16K -> 8K: GEMM2 per m in two halves (epi1 jt0-3 -> write 2 rows ->
//     GEMM2 kt0,1 -> epi1 jt4-7 -> same rows -> GEMM2 kt2,3); same-wave DS
//     in-order makes buffer reuse safe; all indices static (rule #20).
// (b) sDist deleted (recompute from sRel at epi1). LDS = 40448 <= 40960.
// (c) GEMM1 per-m: acc1[8] = 32 AGPR (was 64). Peak regs ~112-120 <= 128 ->
//     4 waves/SIMD. Cost: wx1f A-frags read twice per tile. Prefetch E moves
//     after GEMM1(m=1)'s sG reads; cover = epi1(1)+GEMM2(1)+scatter(1).
__global__ __launch_bounds__(256, 4) void node_kernel(
    const unsigned char* __restrict__ ws, float* __restrict__ out) {
  __shared__ uint4 sG[1024];                      // 16 KB row-gather frags
  __shared__ uint4 sH[512];                       // 8 KB h frags (2 rows/wave)
  __shared__ __align__(16) float sAccX[NB * 68];  // 8.7 KB; cols 64..66 = pos
  __shared__ unsigned char xbCol[4096];           // 4 KB block col features
  __shared__ float4 sPosC[NB];                    // 512 B block col posw
  __shared__ unsigned int sRC[ET];                // 512 B packed (lc<<17|r)
  __shared__ float sW[ET];                        // 512 B
  __shared__ float sRel[ET * 3];                  // 1.5 KB

  const int tid = threadIdx.x;
  const int lane = tid & 63;
  const int wave = tid >> 6;
  const int q = lane >> 4;
  const int nn = lane & 15;
  const int base = blockIdx.x * NB;
  const int et0 = wave * 2;
  const int W32 = wave * 32;

  const int* off = (const int*)(ws + WS_OFF);
  const unsigned int* srec = (const unsigned int*)(ws + WS_SREC);
  const uint4* wx1f = (const uint4*)(ws + WS_WX1);
  const uint4* wx2f = (const uint4*)(ws + WS_WX2);
  const float* misc = (const float*)(ws + WS_MISC);
  const float* posw = (const float*)(ws + WS_POSW);
  const unsigned char* xb = ws + WS_XB;

  const int e0 = off[base];
  const int e1 = off[base + NB];

  // ---- block staging: xbCol (swizzled), sPosC, zero sAccX
  {
    const int row = tid >> 3;
    const int o = (tid & 7) << 4;
    const uint4 v = *(const uint4*)(xb + (size_t)(base + row) * 128 + o);
    *(uint4*)(xbCol + (row << 7) + (o ^ ((row & 7) << 4))) = v;
  }
  if (tid < NB) sPosC[tid] = *(const float4*)(posw + 4 * (size_t)(base + tid));
  for (int i = tid; i < NB * 68; i += 256) sAccX[i] = 0.f;

  // ---- prologue: tile-0 record + posw[r]
  unsigned int prec = 0;
  if (lane < 32) {
    int e = e0 + W32 + lane;
    e = e < EDGES ? e : EDGES - 1;
    prec = srec[e];
  }
  unsigned int rec0 = __shfl(prec, nn);
  unsigned int rec1 = __shfl(prec, 16 + nn);
  float4 pR = {0.f, 0.f, 0.f, 0.f};
  if (lane < 32) pR = *(const float4*)(posw + 4 * (size_t)(prec & 0x1FFFFu));
  __syncthreads();  // staging visible; also drains vmcnt (prec/pR done)

  // ---- issue tile-0 row gloads (stay in flight into iter 0)
  {
    const int ko = (lane >> 4) << 4;
#pragma unroll
    for (int mm = 0; mm < 2; ++mm) {
      const unsigned int rr = mm ? rec1 : rec0;
      const unsigned char* g0 = xb + ((size_t)(rr & 0x1FFFFu) << 7) + ko;
      gload16(g0, &sG[((et0 + mm) * 2 + 0) * 64]);
      gload16(g0 + 64, &sG[((et0 + mm) * 2 + 1) * 64]);
    }
  }

  const floatx4 fzero = {0.f, 0.f, 0.f, 0.f};

#pragma unroll 1
  for (int t0 = e0; t0 < e1; t0 += ET) {
    // ---- A: wave-own metadata -> LDS (pC from sPosC; pR prefetched)
    if (lane < 32) {
      const int j = W32 + lane;
      const float4 pc = sPosC[prec >> 17];
      sRC[j] = prec;
      sW[j] = pR.w;
      sRel[3 * j + 0] = pR.x - pc.x;
      sRel[3 * j + 1] = pR.y - pc.y;
      sRel[3 * j + 2] = pR.z - pc.z;
    }

    // ---- B: issue next tile's srec
    unsigned int rcN = 0;
    if (lane < 32) {
      int e = t0 + ET + W32 + lane;
      e = e < EDGES ? e : EDGES - 1;
      rcN = srec[e];
    }

    // ---- C: row gloads for THIS tile landed (rcN still in flight)
    asm volatile("s_waitcnt vmcnt(1)" ::: "memory");
    __builtin_amdgcn_sched_barrier(0);

    // ---- per-m pipeline: GEMM1(m) -> [E at m=1] -> epi1+GEMM2 halves -> scatter
#pragma unroll
    for (int m = 0; m < 2; ++m) {
      const unsigned int recm = m ? rec1 : rec0;
      // GEMM1(m): kt0,1 B from sG (gload rows); kt2,3 B from xbCol
      floatx4 acc1[8];
#pragma unroll
      for (int j = 0; j < 8; ++j) acc1[j] = fzero;
#pragma unroll 1
      for (int kt = 0; kt < 2; ++kt) {
        const short8 b = __builtin_bit_cast(short8, sG[((et0 + m) * 2 + kt) * 64 + lane]);
#pragma unroll
        for (int jt = 0; jt < 8; ++jt) {
          const short8 a = __builtin_bit_cast(short8, wx1f[(kt * 8 + jt) * 64 + lane]);
          acc1[jt] = MFMA(a, b, acc1[jt]);
        }
      }
      {
        const int lcm = (int)(recm >> 17);
#pragma unroll 1
        for (int kt = 2; kt < 4; ++kt) {
          const int o = ((kt & 1) << 6) | ((lane >> 4) << 4);
          const short8 b =
              *(const short8*)(xbCol + (lcm << 7) + (o ^ ((lcm & 7) << 4)));
#pragma unroll
          for (int jt = 0; jt < 8; ++jt) {
            const short8 a = __builtin_bit_cast(short8, wx1f[(kt * 8 + jt) * 64 + lane]);
            acc1[jt] = MFMA(a, b, acc1[jt]);
          }
        }
      }

      // E (once, after m=1's sG reads): next-tile prefetch
      if (m == 1) {
        __builtin_amdgcn_sched_barrier(0);
        if (lane < 32) pR = *(const float4*)(posw + 4 * (size_t)(rcN & 0x1FFFFu));
        const unsigned int rec0n = __shfl(rcN, nn);
        const unsigned int rec1n = __shfl(rcN, 16 + nn);
        const int ko = (lane >> 4) << 4;
#pragma unroll
        for (int mm = 0; mm < 2; ++mm) {
          const unsigned int rr = mm ? rec1n : rec0n;
          const unsigned char* g0 = xb + ((size_t)(rr & 0x1FFFFu) << 7) + ko;
          gload16(g0, &sG[((et0 + mm) * 2 + 0) * 64]);
          gload16(g0 + 64, &sG[((et0 + mm) * 2 + 1) * 64]);
        }
        rec0 = rec0n;
        rec1 = rec1n;
        prec = rcN;
      }

      // epi1(m) + GEMM2(m) in two halves through the 2-row sH buffer
      const int el = (et0 + m) * 16 + nn;
      const float r0e = sRel[3 * el + 0];
      const float r1e = sRel[3 * el + 1];
      const float r2e = sRel[3 * el + 2];
      const float dist = r0e * r0e + r1e * r1e + r2e * r2e;
      floatx4 a20 = fzero, a21 = fzero, a22 = fzero, a23 = fzero;
#pragma unroll
      for (int g = 0; g < 2; ++g) {
#pragma unroll
        for (int jj = 0; jj < 4; ++jj) {
          const int jt = g * 4 + jj;
          const float4 bx = *(const float4*)(misc + 0 + jt * 16 + q * 4);
          const float4 wd = *(const float4*)(misc + 456 + jt * 16 + q * 4);
          const unsigned int h01 = cvtpk2bf(fast_silu(acc1[jt][0] + bx.x + dist * wd.x),
                                            fast_silu(acc1[jt][1] + bx.y + dist * wd.y));
          const unsigned int h23 = cvtpk2bf(fast_silu(acc1[jt][2] + bx.z + dist * wd.z),
                                            fast_silu(acc1[jt][3] + bx.w + dist * wd.w));
          const int j0 = jj * 16 + q * 4;  // local 0..63
          const int kt2 = j0 >> 5;
          const int lane2 = (((j0 & 31) >> 3) << 4) | nn;
          const int byteoff = (j0 & 7) << 1;
          uint2* dst = (uint2*)((char*)sH +
                                (((size_t)((wave * 2 + kt2) * 64 + lane2)) << 4) + byteoff);
          *dst = make_uint2(h01, h23);
        }
#pragma unroll
        for (int ktl = 0; ktl < 2; ++ktl) {
          const short8 b = __builtin_bit_cast(short8, sH[(wave * 2 + ktl) * 64 + lane]);
          const int kk = g * 2 + ktl;
          a20 = MFMA(__builtin_bit_cast(short8, wx2f[(kk * 4 + 0) * 64 + lane]), b, a20);
          a21 = MFMA(__builtin_bit_cast(short8, wx2f[(kk * 4 + 1) * 64 + lane]), b, a21);
          a22 = MFMA(__builtin_bit_cast(short8, wx2f[(kk * 4 + 2) * 64 + lane]), b, a22);
          a23 = MFMA(__builtin_bit_cast(short8, wx2f[(kk * 4 + 3) * 64 + lane]), b, a23);
        }
      }

      // scatter(m): masks + pos + x-features
      const bool vE = (t0 + el) < e1;
      int lcv = (int)(sRC[el] >> 17);
      if (!vE) lcv = -1 - nn;  // singleton segments for invalid lanes
      // unconditional DPPs (convergent!) then bitwise combines:
      const int k1 = dpp_i<0x111>(lcv);
      const int k2 = dpp_i<0x112>(lcv);
      const int k4 = dpp_i<0x114>(lcv);
      const int k8 = dpp_i<0x118>(lcv);
      const int kn = dpp_i<0x101>(lcv);
      const bool m1 = (nn >= 1) & (k1 == lcv);
      const bool m2 = (nn >= 2) & (k2 == lcv);
      const bool m4 = (nn >= 4) & (k4 == lcv);
      const bool m8 = (nn >= 8) & (k8 == lcv);
      const bool tail = vE & ((nn == 15) | (kn != lcv));

      // pos update (w precomputed per node)
      const float wv = sW[el];
      float p0 = segscan(wv * r0e, m1, m2, m4, m8);
      float p1 = segscan(wv * r1e, m1, m2, m4, m8);
      float p2 = segscan(wv * r2e, m1, m2, m4, m8);
      if (tail && q == 0) {
        float* ap = sAccX + lcv * 68 + 64;  // pos acc lives in the pad
        lds_add(ap + 0, p0);
        lds_add(ap + 1, p1);
        lds_add(ap + 2, p2);
      }
      {
        const float4 b2 = *(const float4*)(misc + 128 + 0 * 16 + q * 4);
        float v0 = segscan(a20[0] + b2.x, m1, m2, m4, m8);
        float v1 = segscan(a20[1] + b2.y, m1, m2, m4, m8);
        float v2 = segscan(a20[2] + b2.z, m1, m2, m4, m8);
        float v3 = segscan(a20[3] + b2.w, m1, m2, m4, m8);
        if (tail) {
          float* arow = sAccX + lcv * 68 + q * 4;
          lds_add(arow + 0, v0);
          lds_add(arow + 1, v1);
          lds_add(arow + 2, v2);
          lds_add(arow + 3, v3);
        }
      }
      {
        const float4 b2 = *(const float4*)(misc + 128 + 1 * 16 + q * 4);
        float v0 = segscan(a21[0] + b2.x, m1, m2, m4, m8);
        float v1 = segscan(a21[1] + b2.y, m1, m2, m4, m8);
        float v2 = segscan(a21[2] + b2.z, m1, m2, m4, m8);
        float v3 = segscan(a21[3] + b2.w, m1, m2, m4, m8);
        if (tail) {
          float* arow = sAccX + lcv * 68 + 16 + q * 4;
          lds_add(arow + 0, v0);
          lds_add(arow + 1, v1);
          lds_add(arow + 2, v2);
          lds_add(arow + 3, v3);
        }
      }
      {
        const float4 b2 = *(const float4*)(misc + 128 + 2 * 16 + q * 4);
        float v0 = segscan(a22[0] + b2.x, m1, m2, m4, m8);
        float v1 = segscan(a22[1] + b2.y, m1, m2, m4, m8);
        float v2 = segscan(a22[2] + b2.z, m1, m2, m4, m8);
        float v3 = segscan(a22[3] + b2.w, m1, m2, m4, m8);
        if (tail) {
          float* arow = sAccX + lcv * 68 + 32 + q * 4;
          lds_add(arow + 0, v0);
          lds_add(arow + 1, v1);
          lds_add(arow + 2, v2);
          lds_add(arow + 3, v3);
        }
      }
      {
        const float4 b2 = *(const float4*)(misc + 128 + 3 * 16 + q * 4);
        float v0 = segscan(a23[0] + b2.x, m1, m2, m4, m8);
        float v1 = segscan(a23[1] + b2.y, m1, m2, m4, m8);
        float v2 = segscan(a23[2] + b2.z, m1, m2, m4, m8);
        float v3 = segscan(a23[3] + b2.w, m1, m2, m4, m8);
        if (tail) {
          float* arow = sAccX + lcv * 68 + 48 + q * 4;
          lds_add(arow + 0, v0);
          lds_add(arow + 1, v1);
          lds_add(arow + 2, v2);
          lds_add(arow + 3, v3);
        }
      }
    }
    // no end-of-loop barrier: all in-loop LDS arrays are wave-own slots.
  }
  __syncthreads();  // all waves' LDS-atomic accumulates done

  // ---- final coalesced stores (no global atomics); NODES % NB == 0
  {
    const int n = base + (tid >> 3);
    const int c0 = (tid & 7) * 8;
    float* orow = out + (size_t)n * 64 + c0;
    const float* arow = sAccX + (tid >> 3) * 68 + c0;
    *(float4*)(orow + 0) = *(const float4*)(arow + 0);
    *(float4*)(orow + 4) = *(const float4*)(arow + 4);
    if (tid < NB * 3)
      out[(size_t)NODES * 64 + base * 3 + tid] = sAccX[(tid / 3) * 68 + 64 + (tid % 3)];
  }
}

extern "C" void kernel_launch(void* const* d_in, const int* in_sizes, int n_in,
                              void* d_out, int out_size, void* d_ws, size_t ws_size,
                              hipStream_t stream) {
  (void)in_sizes; (void)n_in; (void)ws_size; (void)out_size;
  const float* x = (const float*)d_in[0];
  const float* pos = (const float*)d_in[1];
  const int* ei = (const int*)d_in[2];
  const float* Wx1 = (const float*)d_in[3];
  const float* bx1 = (const float*)d_in[4];
  const float* Wx2 = (const float*)d_in[5];
  const float* bx2 = (const float*)d_in[6];
  const float* Wp1 = (const float*)d_in[7];
  const float* bp1 = (const float*)d_in[8];
  const float* Wp2 = (const float*)d_in[9];
  const float* bp2 = (const float*)d_in[10];
  float* out = (float*)d_out;
  unsigned char* ws = (unsigned char*)d_ws;

  int* counts = (int*)(ws + WS_CNT);   // aliased with cursor (scan3 rewrites)
  int* cursor = (int*)(ws + WS_CNT);
  int* off = (int*)(ws + WS_OFF);
  int* tmp = (int*)(ws + WS_TMP);      // aliased with srec (dies before scatter)
  int* bsum = (int*)(ws + WS_BSUM);
  unsigned int* srec = (unsigned int*)(ws + WS_SREC);

  prep_kernel<<<64, 256, 0, stream>>>(Wx1, Wx2, Wp1, bx1, bx2, bp1, Wp2, bp2, ws);
  wpos_kernel<<<NBW, 256, 0, stream>>>(x, pos, ei, ws);  // + folded hist
  scan1_kernel<<<SCB, 1024, 0, stream>>>(counts, tmp, bsum);
  scan3_kernel<<<SCB, 1024, 0, stream>>>(counts, tmp, bsum, off, cursor);
  const int eb = (EDGES + 255) / 256;
  scatter_kernel<<<eb, 256, 0, stream>>>(ei, cursor, srec);
  node_kernel<<<NBLK, 256, 0, stream>>>(ws, out);
}

// Round 10
// 449.928 us; speedup vs baseline: 1.0744x; 1.0744x over previous
//
#include <hip/hip_runtime.h>

#define EDGES 1000000
#define NODES 100000
#define ET 128   // edges per tile (4 waves x 32)
#define NB 32    // nodes per block (node_kernel); 100000 % 32 == 0
#define NBLK (NODES / NB)             // 3125
#define NBW ((NODES + 127) / 128)     // 782 wpos blocks

typedef short short8 __attribute__((ext_vector_type(8)));
typedef float floatx4 __attribute__((ext_vector_type(4)));
typedef unsigned int u32x2 __attribute__((ext_vector_type(2)));
typedef unsigned int u32x4 __attribute__((ext_vector_type(4)));

#define MFMA(a, b, c) __builtin_amdgcn_mfma_f32_16x16x32_bf16(a, b, c, 0, 0, 0)

// ws layout (bytes)
#define WS_WX1 0         // 32768: Wx1 bf16 frags
#define WS_WX2 32768     // 16384: Wx2 frags
#define WS_WP1 49152     // 16384: Wp1 frags
#define WS_MISC 65536    // 2048: biases etc (floats)
#define WS_OFF 68608     // off[100128] int = 400512 B (CSR offsets, padded)
#define WS_CNT 469504    // counts/cursor[100000] int = 400000 B (aliased)
#define WS_SREC 917504   // u32[EDGES] = 4 MB packed sorted records (lc<<17|r)
#define WS_POSW 8917504  // float4[NODES] = 1.6 MB {pos.xyz, w_pos} per node
#define WS_XB 10517504   // bf16[NODES][64] = 12.8 MB x pre-converted to bf16
// bstate aliases the srec region (dead before scatter writes srec):
#define WS_BST WS_SREC                 // u32[128] decoupled-lookback states

__device__ __forceinline__ unsigned short f2bf(float f) {
  union { float f; unsigned int u; } c;
  c.f = f;
  unsigned int u = c.u;
  u += 0x7fffu + ((u >> 16) & 1u);
  return (unsigned short)(u >> 16);
}

__device__ __forceinline__ unsigned int pack2bf(float lo, float hi) {
  return (unsigned int)f2bf(lo) | ((unsigned int)f2bf(hi) << 16);
}

// single-instruction RNE pack (same rounding as f2bf); no builtin on gfx950
__device__ __forceinline__ unsigned int cvtpk2bf(float lo, float hi) {
  unsigned int r;
  asm("v_cvt_pk_bf16_f32 %0, %1, %2" : "=v"(r) : "v"(lo), "v"(hi));
  return r;
}

// global -> LDS direct (16B/lane). LDS dest = uniform base + lane*16;
// global src is per-lane (guide m97/m104/m173).
__device__ __forceinline__ void gload16(const void* g, void* l) {
  __builtin_amdgcn_global_load_lds(
      (const __attribute__((address_space(1))) void*)g,
      (__attribute__((address_space(3))) void*)l, 16, 0, 0);
}

__device__ __forceinline__ float fast_silu(float v) {
#if __has_builtin(__builtin_amdgcn_exp2f) && __has_builtin(__builtin_amdgcn_rcpf)
  float e = __builtin_amdgcn_exp2f(-1.44269504088896340736f * v);
  return v * __builtin_amdgcn_rcpf(1.0f + e);
#else
  return v / (1.0f + __expf(-v));
#endif
}

// DPP cross-lane within 16-lane rows. MUST be called unconditionally in
// straight-line code (convergent ops).
template <int CTRL>
__device__ __forceinline__ int dpp_i(int v) {
  return __builtin_amdgcn_update_dpp(0, v, CTRL, 0xf, 0xf, true);
}
template <int CTRL>
__device__ __forceinline__ float dpp_f(float v) {
  return __builtin_bit_cast(float, dpp_i<CTRL>(__builtin_bit_cast(int, v)));
}

// Segmented inclusive prefix-sum across nn (16-lane row), segments = runs of
// equal sorted keys; masks m1..m8 from unconditional key equality at d=1,2,4,8.
__device__ __forceinline__ float segscan(float v, bool m1, bool m2, bool m4, bool m8) {
  float t;
  t = dpp_f<0x111>(v); v += m1 ? t : 0.f;
  t = dpp_f<0x112>(v); v += m2 ? t : 0.f;
  t = dpp_f<0x114>(v); v += m4 ? t : 0.f;
  t = dpp_f<0x118>(v); v += m8 ? t : 0.f;
  return v;
}

__device__ __forceinline__ void lds_add(float* p, float v) {
  __hip_atomic_fetch_add(p, v, __ATOMIC_RELAXED, __HIP_MEMORY_SCOPE_WORKGROUP);
}

// prep also zero-inits counts and the lookback states
__global__ __launch_bounds__(256) void prep_kernel(
    const float* __restrict__ Wx1, const float* __restrict__ Wx2,
    const float* __restrict__ Wp1, const float* __restrict__ bx1,
    const float* __restrict__ bx2, const float* __restrict__ bp1,
    const float* __restrict__ Wp2, const float* __restrict__ bp2,
    unsigned char* __restrict__ ws) {
  const int t = blockIdx.x * 256 + threadIdx.x;
  const int nthr = gridDim.x * 256;

  int* counts = (int*)(ws + WS_CNT);
  for (int i = t; i < NODES; i += nthr) counts[i] = 0;
  unsigned int* bst = (unsigned int*)(ws + WS_BST);
  if (t < 128) bst[t] = 0;

  for (int task = t; task < 2048; task += nthr) {  // Wx1[0:128][0:128]
    const int n = task & 127;
    const int kb = task >> 7;
    const int k0 = kb << 3;
    unsigned int d[4];
#pragma unroll
    for (int i = 0; i < 4; ++i)
      d[i] = pack2bf(Wx1[(k0 + 2 * i) * 128 + n], Wx1[(k0 + 2 * i + 1) * 128 + n]);
    const int lane = ((kb & 3) << 4) | (n & 15);
    const int frag = ((kb >> 2) << 3) | (n >> 4);
    *(uint4*)(ws + WS_WX1 + ((size_t)(frag * 64 + lane) << 4)) =
        make_uint4(d[0], d[1], d[2], d[3]);
  }
  for (int task = t; task < 1024; task += nthr) {  // Wx2[0:128][0:64]
    const int n = task & 63;
    const int kb = task >> 6;
    const int k0 = kb << 3;
    unsigned int d[4];
#pragma unroll
    for (int i = 0; i < 4; ++i)
      d[i] = pack2bf(Wx2[(k0 + 2 * i) * 64 + n], Wx2[(k0 + 2 * i + 1) * 64 + n]);
    const int lane = ((kb & 3) << 4) | (n & 15);
    const int frag = ((kb >> 2) << 2) | (n >> 4);
    *(uint4*)(ws + WS_WX2 + ((size_t)(frag * 64 + lane) << 4)) =
        make_uint4(d[0], d[1], d[2], d[3]);
  }
  for (int task = t; task < 1024; task += nthr) {  // Wp1[0:64][0:128]
    const int n = task & 127;
    const int kb = task >> 7;
    const int k0 = kb << 3;
    unsigned int d[4];
#pragma unroll
    for (int i = 0; i < 4; ++i)
      d[i] = pack2bf(Wp1[(k0 + 2 * i) * 128 + n], Wp1[(k0 + 2 * i + 1) * 128 + n]);
    const int lane = ((kb & 3) << 4) | (n & 15);
    const int frag = ((kb >> 2) << 3) | (n >> 4);
    *(uint4*)(ws + WS_WP1 + ((size_t)(frag * 64 + lane) << 4)) =
        make_uint4(d[0], d[1], d[2], d[3]);
  }
  float* misc = (float*)(ws + WS_MISC);
  for (int i = t; i < 128; i += nthr) misc[i] = bx1[i];
  for (int i = t; i < 64; i += nthr) misc[128 + i] = bx2[i];
  for (int i = t; i < 128; i += nthr) misc[192 + i] = bp1[i];
  for (int i = t; i < 128; i += nthr) misc[320 + i] = Wp2[i];
  if (t == 0) misc[448] = bp2[0];
  for (int i = t; i < 128; i += nthr) misc[456 + i] = Wx1[128 * 128 + i];
}

// ---- per-NODE phi_pos precompute + x -> bf16 + folded hist ----
__global__ __launch_bounds__(256) void wpos_kernel(
    const float* __restrict__ x, const float* __restrict__ pos,
    const int* __restrict__ ei, unsigned char* __restrict__ ws) {
  __shared__ float sX[128 * 68];  // 34816 B, stride 68 (16B-aligned, low conflict)

  const uint4* wp1f = (const uint4*)(ws + WS_WP1);
  const float* misc = (const float*)(ws + WS_MISC);
  float* posw = (float*)(ws + WS_POSW);
  unsigned char* xb = ws + WS_XB;
  int* counts = (int*)(ws + WS_CNT);

  const int tid = threadIdx.x;
  const int lane = tid & 63;
  const int wave = tid >> 6;
  const int q = lane >> 4;
  const int nn = lane & 15;
  const int B0 = blockIdx.x * 128;
  const int nvalid = (NODES - B0 < 128) ? (NODES - B0) : 128;

  // stage x[B0..B0+128) coalesced: 2048 float4s, 8 per thread
#pragma unroll
  for (int k = 0; k < 8; ++k) {
    const int fidx = tid + k * 256;  // float4 index
    const int row = fidx >> 4, c4 = fidx & 15;
    float4 v = make_float4(0.f, 0.f, 0.f, 0.f);
    if (row < nvalid) v = *(const float4*)(x + ((size_t)(B0 + row)) * 64 + c4 * 4);
    *(float4*)(sX + row * 68 + c4 * 4) = v;
  }
  __syncthreads();

  // xb bf16 copy: 4096 u32 outputs, 16 per thread, coalesced
#pragma unroll
  for (int k = 0; k < 16; ++k) {
    const int pidx = tid + k * 256;           // u32 index
    const int row = pidx >> 5, cp = pidx & 31;  // 32 u32 per 128B row
    if (B0 + row < NODES)
      *(unsigned int*)(xb + ((size_t)(B0 + row)) * 128 + cp * 4) =
          cvtpk2bf(sX[row * 68 + cp * 2], sX[row * 68 + cp * 2 + 1]);
  }

  // B-frags from LDS (invalid rows zero-filled; posw write is guarded)
  const int base = wave * 32;  // node-local base for this wave
  short8 bf[2][2];
#pragma unroll
  for (int m = 0; m < 2; ++m) {
    const int nl = base + m * 16 + nn;
#pragma unroll
    for (int kt = 0; kt < 2; ++kt) {
      const float4 a = *(const float4*)(sX + nl * 68 + kt * 32 + q * 8);
      const float4 b = *(const float4*)(sX + nl * 68 + kt * 32 + q * 8 + 4);
      u32x4 d;
      d[0] = cvtpk2bf(a.x, a.y);
      d[1] = cvtpk2bf(a.z, a.w);
      d[2] = cvtpk2bf(b.x, b.y);
      d[3] = cvtpk2bf(b.z, b.w);
      bf[m][kt] = __builtin_bit_cast(short8, d);
    }
  }

  const floatx4 fzero = {0.f, 0.f, 0.f, 0.f};
  floatx4 accp[2][8];
#pragma unroll
  for (int m = 0; m < 2; ++m)
#pragma unroll
    for (int j = 0; j < 8; ++j) accp[m][j] = fzero;
#pragma unroll 1
  for (int kt = 0; kt < 2; ++kt) {
#pragma unroll
    for (int jt = 0; jt < 8; ++jt) {
      const short8 a = __builtin_bit_cast(short8, wp1f[(kt * 8 + jt) * 64 + lane]);
      accp[0][jt] = MFMA(a, bf[0][kt], accp[0][jt]);
      accp[1][jt] = MFMA(a, bf[1][kt], accp[1][jt]);
    }
  }
#pragma unroll
  for (int m = 0; m < 2; ++m) {
    float s = 0.f;
#pragma unroll
    for (int jt = 0; jt < 8; ++jt) {
      const float4 bp = *(const float4*)(misc + 192 + jt * 16 + q * 4);
      const float4 wp = *(const float4*)(misc + 320 + jt * 16 + q * 4);
      s += fast_silu(accp[m][jt][0] + bp.x) * wp.x;
      s += fast_silu(accp[m][jt][1] + bp.y) * wp.y;
      s += fast_silu(accp[m][jt][2] + bp.z) * wp.z;
      s += fast_silu(accp[m][jt][3] + bp.w) * wp.w;
    }
    s += __shfl_xor(s, 16);
    s += __shfl_xor(s, 32);
    const int node = B0 + base + m * 16 + nn;
    if (q == 0 && node < NODES) {
      float4 o;
      o.x = pos[3 * node + 0];
      o.y = pos[3 * node + 1];
      o.z = pos[3 * node + 2];
      o.w = s + misc[448];
      *(float4*)(posw + 4 * (size_t)node) = o;
    }
  }

  // ---- folded hist (grid-stride; counts zeroed by prep)
  const int gsz = gridDim.x * 256;
  for (int t = blockIdx.x * 256 + tid; t < EDGES; t += gsz) {
    int c = __builtin_nontemporal_load(ei + EDGES + t);
    c = (c < 0) ? 0 : ((c >= NODES) ? NODES - 1 : c);
    atomicAdd(&counts[c], 1);
  }
}

#define SCB 98  // blocks of 1024: 98*1024 = 100352 >= NODES+128

// R19: single-pass scan via decoupled lookback (replaces scan1+scan3).
// bstate[b] = (status<<28)|value; status 1 = aggregate-ready, 2 = prefix-
// ready; values <= 1e6 < 2^28. 98 blocks << 256 CUs so all are schedulable
// regardless of dispatch order; the full-lookback walk terminates as soon
// as predecessors publish aggregates. Device-scope acquire/release atomics
// handle cross-XCD visibility. cursor aliases counts: each block reads its
// own range into LDS before any write; no cross-block counts reads exist.
__global__ __launch_bounds__(1024) void scan_kernel(int* __restrict__ counts,
                                                    unsigned int* __restrict__ bstate,
                                                    int* __restrict__ off,
                                                    int* __restrict__ cursor) {
  __shared__ int part[1024];
  __shared__ int sprefix;
  const int t = threadIdx.x;
  const int b = blockIdx.x;
  const int i = b * 1024 + t;
  const int v = (i < NODES) ? counts[i] : 0;
  part[t] = v;
  __syncthreads();
  for (int d = 1; d < 1024; d <<= 1) {
    int u = 0;
    if (t >= d) u = part[t - d];
    __syncthreads();
    if (t >= d) part[t] += u;
    __syncthreads();
  }
  if (t == 0) {
    const unsigned int agg = (unsigned int)part[1023];
    int prefix = 0;
    if (b == 0) {
      __hip_atomic_store(&bstate[0], (2u << 28) | agg, __ATOMIC_RELEASE,
                         __HIP_MEMORY_SCOPE_AGENT);
    } else {
      __hip_atomic_store(&bstate[b], (1u << 28) | agg, __ATOMIC_RELEASE,
                         __HIP_MEMORY_SCOPE_AGENT);
      int j = b - 1;
      while (true) {
        const unsigned int s = __hip_atomic_load(&bstate[j], __ATOMIC_ACQUIRE,
                                                 __HIP_MEMORY_SCOPE_AGENT);
        const unsigned int st = s >> 28;
        if (st == 2u) { prefix += (int)(s & 0x0FFFFFFFu); break; }
        if (st == 1u) { prefix += (int)(s & 0x0FFFFFFFu); --j; }
        // st == 0: spin
      }
      __hip_atomic_store(&bstate[b], (2u << 28) | (unsigned int)(prefix + (int)agg),
                         __ATOMIC_RELEASE, __HIP_MEMORY_SCOPE_AGENT);
    }
    sprefix = prefix;
  }
  __syncthreads();
  if (i < NODES) {
    const int o = sprefix + part[t] - v;
    off[i] = o;
    cursor[i] = o;  // aliased with counts; v already read
  } else if (i < NODES + 128) {
    off[i] = EDGES;
  }
}

// packed record — lc = c & 31 (NB=32; block base is (c>>5)*32), r < 2^17.
__global__ __launch_bounds__(256) void scatter_kernel(const int* __restrict__ ei,
                                                      int* __restrict__ cursor,
                                                      unsigned int* __restrict__ srec) {
  const int t = blockIdx.x * 256 + threadIdx.x;
  if (t < EDGES) {
    int r = __builtin_nontemporal_load(ei + t);
    int c = __builtin_nontemporal_load(ei + EDGES + t);
    r = (r < 0) ? 0 : ((r >= NODES) ? NODES - 1 : r);
    c = (c < 0) ? 0 : ((c >= NODES) ? NODES - 1 : c);
    const int p = atomicAdd(&cursor[c], 1);
    __builtin_nontemporal_store(((unsigned)(c & 31) << 17) | (unsigned)r, srec + p);
  }
}

// ---- main: node-centric, zero global atomics, zero in-loop barriers ----
// R19 = exact R17 revert (proven 220 µs). R18's occupancy push (per-m GEMM1,
// 2-row sH) regressed −25%: occupancy rose 30.7->39% but VALUBusy fell
// 43->33% — the per-m split halved MFMA ILP and added sH write->read->write
// turnarounds; occupancy bought by serializing the per-wave pipeline loses.
// Structure: cols block-local in xbCol (swizzled, staged once); rows via
// global_load_lds from bf16 xb; vmcnt(1)+sched_barrier guards gload->ds_read;
// F/G per-m with h streamed to sH and 4 NAMED GEMM2 accumulators (no
// runtime-indexed register arrays, rule #20); all in-loop LDS slots wave-own.
__global__ __launch_bounds__(256, 3) void node_kernel(
    const unsigned char* __restrict__ ws, float* __restrict__ out) {
  __shared__ uint4 sG[1024];                      // 16 KB row-gather frags
  __shared__ uint4 sH[1024];                      // 16 KB h frags (4 rows/wave)
  __shared__ __align__(16) float sAccX[NB * 68];  // 8.7 KB; cols 64..66 = pos
  __shared__ unsigned char xbCol[4096];           // 4 KB block col features
  __shared__ float4 sPosC[NB];                    // 512 B block col posw
  __shared__ unsigned int sRC[ET];                // 512 B packed (lc<<17|r)
  __shared__ float sW[ET];                        // 512 B
  __shared__ float sRel[ET * 3];                  // 1.5 KB
  __shared__ float sDist[ET];                     // 512 B

  const int tid = threadIdx.x;
  const int lane = tid & 63;
  const int wave = tid >> 6;
  const int q = lane >> 4;
  const int nn = lane & 15;
  const int base = blockIdx.x * NB;
  const int et0 = wave * 2;
  const int W32 = wave * 32;

  const int* off = (const int*)(ws + WS_OFF);
  const unsigned int* srec = (const unsigned int*)(ws + WS_SREC);
  const uint4* wx1f = (const uint4*)(ws + WS_WX1);
  const uint4* wx2f = (const uint4*)(ws + WS_WX2);
  const float* misc = (const float*)(ws + WS_MISC);
  const float* posw = (const float*)(ws + WS_POSW);
  const unsigned char* xb = ws + WS_XB;

  const int e0 = off[base];
  const int e1 = off[base + NB];

  // ---- block staging: xbCol (swizzled), sPosC, zero sAccX
  {
    const int row = tid >> 3;
    const int o = (tid & 7) << 4;
    const uint4 v = *(const uint4*)(xb + (size_t)(base + row) * 128 + o);
    *(uint4*)(xbCol + (row << 7) + (o ^ ((row & 7) << 4))) = v;
  }
  if (tid < NB) sPosC[tid] = *(const float4*)(posw + 4 * (size_t)(base + tid));
  for (int i = tid; i < NB * 68; i += 256) sAccX[i] = 0.f;

  // ---- prologue: tile-0 record + posw[r]
  unsigned int prec = 0;
  if (lane < 32) {
    int e = e0 + W32 + lane;
    e = e < EDGES ? e : EDGES - 1;
    prec = srec[e];
  }
  unsigned int rec0 = __shfl(prec, nn);
  unsigned int rec1 = __shfl(prec, 16 + nn);
  float4 pR = {0.f, 0.f, 0.f, 0.f};
  if (lane < 32) pR = *(const float4*)(posw + 4 * (size_t)(prec & 0x1FFFFu));
  __syncthreads();  // staging visible; also drains vmcnt (prec/pR done)

  // ---- issue tile-0 row gloads (stay in flight into iter 0)
  {
    const int ko = (lane >> 4) << 4;
#pragma unroll
    for (int mm = 0; mm < 2; ++mm) {
      const unsigned int rr = mm ? rec1 : rec0;
      const unsigned char* g0 = xb + ((size_t)(rr & 0x1FFFFu) << 7) + ko;
      gload16(g0, &sG[((et0 + mm) * 2 + 0) * 64]);
      gload16(g0 + 64, &sG[((et0 + mm) * 2 + 1) * 64]);
    }
  }

  const floatx4 fzero = {0.f, 0.f, 0.f, 0.f};

#pragma unroll 1
  for (int t0 = e0; t0 < e1; t0 += ET) {
    // ---- A: wave-own metadata -> LDS (pC from sPosC; pR prefetched)
    if (lane < 32) {
      const int j = W32 + lane;
      const float4 pc = sPosC[prec >> 17];
      const float r0 = pR.x - pc.x;
      const float r1 = pR.y - pc.y;
      const float r2 = pR.z - pc.z;
      sRC[j] = prec;
      sW[j] = pR.w;
      sRel[3 * j + 0] = r0;
      sRel[3 * j + 1] = r1;
      sRel[3 * j + 2] = r2;
      sDist[j] = r0 * r0 + r1 * r1 + r2 * r2;
    }

    // ---- B: issue next tile's srec
    unsigned int rcN = 0;
    if (lane < 32) {
      int e = t0 + ET + W32 + lane;
      e = e < EDGES ? e : EDGES - 1;
      rcN = srec[e];
    }

    // ---- C: row gloads for THIS tile landed (rcN still in flight)
    asm volatile("s_waitcnt vmcnt(1)" ::: "memory");
    __builtin_amdgcn_sched_barrier(0);

    // ---- D: GEMM1 — kt0,1 B from sG (gload rows); kt2,3 B from xbCol
    floatx4 acc1[2][8];
#pragma unroll
    for (int m = 0; m < 2; ++m)
#pragma unroll
      for (int j = 0; j < 8; ++j) acc1[m][j] = fzero;
#pragma unroll 1
    for (int kt = 0; kt < 2; ++kt) {
      const short8 b0 = __builtin_bit_cast(short8, sG[((et0 + 0) * 2 + kt) * 64 + lane]);
      const short8 b1 = __builtin_bit_cast(short8, sG[((et0 + 1) * 2 + kt) * 64 + lane]);
#pragma unroll
      for (int jt = 0; jt < 8; ++jt) {
        const short8 a = __builtin_bit_cast(short8, wx1f[(kt * 8 + jt) * 64 + lane]);
        acc1[0][jt] = MFMA(a, b0, acc1[0][jt]);
        acc1[1][jt] = MFMA(a, b1, acc1[1][jt]);
      }
    }
    {
      const int lc0 = (int)(rec0 >> 17);
      const int lc1 = (int)(rec1 >> 17);
#pragma unroll 1
      for (int kt = 2; kt < 4; ++kt) {
        const int o = ((kt & 1) << 6) | ((lane >> 4) << 4);
        const short8 b0 =
            *(const short8*)(xbCol + (lc0 << 7) + (o ^ ((lc0 & 7) << 4)));
        const short8 b1 =
            *(const short8*)(xbCol + (lc1 << 7) + (o ^ ((lc1 & 7) << 4)));
#pragma unroll
        for (int jt = 0; jt < 8; ++jt) {
          const short8 a = __builtin_bit_cast(short8, wx1f[(kt * 8 + jt) * 64 + lane]);
          acc1[0][jt] = MFMA(a, b0, acc1[0][jt]);
          acc1[1][jt] = MFMA(a, b1, acc1[1][jt]);
        }
      }
    }

    // ---- E: next-tile prefetch (sG rows free; cover = F+G)
    __builtin_amdgcn_sched_barrier(0);
    {
      if (lane < 32) pR = *(const float4*)(posw + 4 * (size_t)(rcN & 0x1FFFFu));
      const unsigned int rec0n = __shfl(rcN, nn);
      const unsigned int rec1n = __shfl(rcN, 16 + nn);
      const int ko = (lane >> 4) << 4;
#pragma unroll
      for (int mm = 0; mm < 2; ++mm) {
        const unsigned int rr = mm ? rec1n : rec0n;
        const unsigned char* g0 = xb + ((size_t)(rr & 0x1FFFFu) << 7) + ko;
        gload16(g0, &sG[((et0 + mm) * 2 + 0) * 64]);
        gload16(g0 + 64, &sG[((et0 + mm) * 2 + 1) * 64]);
      }
      rec0 = rec0n;
      rec1 = rec1n;
      prec = rcN;
    }

    // ---- F+G per m: epi1(m)->sH direct, GEMM2(m) named accs, scatter(m)
#pragma unroll
    for (int m = 0; m < 2; ++m) {
      const int el = (et0 + m) * 16 + nn;
      const float dist = sDist[el];
      // epi1(m): 8 static jt, stream h straight to sH rows wave*4+kt2
#pragma unroll
      for (int jt = 0; jt < 8; ++jt) {
        const float4 bx = *(const float4*)(misc + 0 + jt * 16 + q * 4);
        const float4 wd = *(const float4*)(misc + 456 + jt * 16 + q * 4);
        const unsigned int h01 = cvtpk2bf(fast_silu(acc1[m][jt][0] + bx.x + dist * wd.x),
                                          fast_silu(acc1[m][jt][1] + bx.y + dist * wd.y));
        const unsigned int h23 = cvtpk2bf(fast_silu(acc1[m][jt][2] + bx.z + dist * wd.z),
                                          fast_silu(acc1[m][jt][3] + bx.w + dist * wd.w));
        const int j0 = jt * 16 + q * 4;  // 0..127
        const int kt2 = j0 >> 5;
        const int lane2 = (((j0 & 31) >> 3) << 4) | nn;
        const int byteoff = (j0 & 7) << 1;
        uint2* dst = (uint2*)((char*)sH +
                              (((size_t)((wave * 4 + kt2) * 64 + lane2)) << 4) + byteoff);
        *dst = make_uint2(h01, h23);
      }
      // GEMM2(m): 4 named accumulators (16 AGPR)
      floatx4 a20 = fzero, a21 = fzero, a22 = fzero, a23 = fzero;
#pragma unroll 1
      for (int kt = 0; kt < 4; ++kt) {
        const short8 b = __builtin_bit_cast(short8, sH[(wave * 4 + kt) * 64 + lane]);
        a20 = MFMA(__builtin_bit_cast(short8, wx2f[(kt * 4 + 0) * 64 + lane]), b, a20);
        a21 = MFMA(__builtin_bit_cast(short8, wx2f[(kt * 4 + 1) * 64 + lane]), b, a21);
        a22 = MFMA(__builtin_bit_cast(short8, wx2f[(kt * 4 + 2) * 64 + lane]), b, a22);
        a23 = MFMA(__builtin_bit_cast(short8, wx2f[(kt * 4 + 3) * 64 + lane]), b, a23);
      }
      // scatter(m): masks + pos + x-features
      const bool vE = (t0 + el) < e1;
      int lcv = (int)(sRC[el] >> 17);
      if (!vE) lcv = -1 - nn;  // singleton segments for invalid lanes
      // unconditional DPPs (convergent!) then bitwise combines:
      const int k1 = dpp_i<0x111>(lcv);
      const int k2 = dpp_i<0x112>(lcv);
      const int k4 = dpp_i<0x114>(lcv);
      const int k8 = dpp_i<0x118>(lcv);
      const int kn = dpp_i<0x101>(lcv);
      const bool m1 = (nn >= 1) & (k1 == lcv);
      const bool m2 = (nn >= 2) & (k2 == lcv);
      const bool m4 = (nn >= 4) & (k4 == lcv);
      const bool m8 = (nn >= 8) & (k8 == lcv);
      const bool tail = vE & ((nn == 15) | (kn != lcv));

      // pos update (w precomputed per node)
      const float wv = sW[el];
      float p0 = segscan(wv * sRel[3 * el + 0], m1, m2, m4, m8);
      float p1 = segscan(wv * sRel[3 * el + 1], m1, m2, m4, m8);
      float p2 = segscan(wv * sRel[3 * el + 2], m1, m2, m4, m8);
      if (tail && q == 0) {
        float* ap = sAccX + lcv * 68 + 64;  // pos acc lives in the pad
        lds_add(ap + 0, p0);
        lds_add(ap + 1, p1);
        lds_add(ap + 2, p2);
      }
      {
        const float4 b2 = *(const float4*)(misc + 128 + 0 * 16 + q * 4);
        float v0 = segscan(a20[0] + b2.x, m1, m2, m4, m8);
        float v1 = segscan(a20[1] + b2.y, m1, m2, m4, m8);
        float v2 = segscan(a20[2] + b2.z, m1, m2, m4, m8);
        float v3 = segscan(a20[3] + b2.w, m1, m2, m4, m8);
        if (tail) {
          float* arow = sAccX + lcv * 68 + q * 4;
          lds_add(arow + 0, v0);
          lds_add(arow + 1, v1);
          lds_add(arow + 2, v2);
          lds_add(arow + 3, v3);
        }
      }
      {
        const float4 b2 = *(const float4*)(misc + 128 + 1 * 16 + q * 4);
        float v0 = segscan(a21[0] + b2.x, m1, m2, m4, m8);
        float v1 = segscan(a21[1] + b2.y, m1, m2, m4, m8);
        float v2 = segscan(a21[2] + b2.z, m1, m2, m4, m8);
        float v3 = segscan(a21[3] + b2.w, m1, m2, m4, m8);
        if (tail) {
          float* arow = sAccX + lcv * 68 + 16 + q * 4;
          lds_add(arow + 0, v0);
          lds_add(arow + 1, v1);
          lds_add(arow + 2, v2);
          lds_add(arow + 3, v3);
        }
      }
      {
        const float4 b2 = *(const float4*)(misc + 128 + 2 * 16 + q * 4);
        float v0 = segscan(a22[0] + b2.x, m1, m2, m4, m8);
        float v1 = segscan(a22[1] + b2.y, m1, m2, m4, m8);
        float v2 = segscan(a22[2] + b2.z, m1, m2, m4, m8);
        float v3 = segscan(a22[3] + b2.w, m1, m2, m4, m8);
        if (tail) {
          float* arow = sAccX + lcv * 68 + 32 + q * 4;
          lds_add(arow + 0, v0);
          lds_add(arow + 1, v1);
          lds_add(arow + 2, v2);
          lds_add(arow + 3, v3);
        }
      }
      {
        const float4 b2 = *(const float4*)(misc + 128 + 3 * 16 + q * 4);
        float v0 = segscan(a23[0] + b2.x, m1, m2, m4, m8);
        float v1 = segscan(a23[1] + b2.y, m1, m2, m4, m8);
        float v2 = segscan(a23[2] + b2.z, m1, m2, m4, m8);
        float v3 = segscan(a23[3] + b2.w, m1, m2, m4, m8);
        if (tail) {
          float* arow = sAccX + lcv * 68 + 48 + q * 4;
          lds_add(arow + 0, v0);
          lds_add(arow + 1, v1);
          lds_add(arow + 2, v2);
          lds_add(arow + 3, v3);
        }
      }
    }
    // no end-of-loop barrier: all in-loop LDS arrays are wave-own slots.
  }
  __syncthreads();  // all waves' LDS-atomic accumulates done

  // ---- final coalesced stores (no global atomics); NODES % NB == 0
  {
    const int n = base + (tid >> 3);
    const int c0 = (tid & 7) * 8;
    float* orow = out + (size_t)n * 64 + c0;
    const float* arow = sAccX + (tid >> 3) * 68 + c0;
    *(float4*)(orow + 0) = *(const float4*)(arow + 0);
    *(float4*)(orow + 4) = *(const float4*)(arow + 4);
    if (tid < NB * 3)
      out[(size_t)NODES * 64 + base * 3 + tid] = sAccX[(tid / 3) * 68 + 64 + (tid % 3)];
  }
}

extern "C" void kernel_launch(void* const* d_in, const int* in_sizes, int n_in,
                              void* d_out, int out_size, void* d_ws, size_t ws_size,
                              hipStream_t stream) {
  (void)in_sizes; (void)n_in; (void)ws_size; (void)out_size;
  const float* x = (const float*)d_in[0];
  const float* pos = (const float*)d_in[1];
  const int* ei = (const int*)d_in[2];
  const float* Wx1 = (const float*)d_in[3];
  const float* bx1 = (const float*)d_in[4];
  const float* Wx2 = (const float*)d_in[5];
  const float* bx2 = (const float*)d_in[6];
  const float* Wp1 = (const float*)d_in[7];
  const float* bp1 = (const float*)d_in[8];
  const float* Wp2 = (const float*)d_in[9];
  const float* bp2 = (const float*)d_in[10];
  float* out = (float*)d_out;
  unsigned char* ws = (unsigned char*)d_ws;

  int* counts = (int*)(ws + WS_CNT);   // aliased with cursor (scan rewrites)
  int* cursor = (int*)(ws + WS_CNT);
  int* off = (int*)(ws + WS_OFF);
  unsigned int* bstate = (unsigned int*)(ws + WS_BST);  // aliases srec (dead by scatter)
  unsigned int* srec = (unsigned int*)(ws + WS_SREC);

  prep_kernel<<<64, 256, 0, stream>>>(Wx1, Wx2, Wp1, bx1, bx2, bp1, Wp2, bp2, ws);
  wpos_kernel<<<NBW, 256, 0, stream>>>(x, pos, ei, ws);  // + folded hist
  scan_kernel<<<SCB, 1024, 0, stream>>>(counts, bstate, off, cursor);
  const int eb = (EDGES + 255) / 256;
  scatter_kernel<<<eb, 256, 0, stream>>>(ei, cursor, srec);
  node_kernel<<<NBLK, 256, 0, stream>>>(ws, out);
}

// Round 13
// 435.265 us; speedup vs baseline: 1.1106x; 1.0337x over previous
//
#include <hip/hip_runtime.h>

#define EDGES 1000000
#define NODES 100000
#define ET 128   // edges per tile (4 waves x 32)
#define NB 32    // nodes per block (node_kernel); 100000 % 32 == 0
#define NBLK (NODES / NB)             // 3125
#define NBW ((NODES + 127) / 128)     // 782 wpos blocks

typedef short short8 __attribute__((ext_vector_type(8)));
typedef float floatx4 __attribute__((ext_vector_type(4)));
typedef unsigned int u32x2 __attribute__((ext_vector_type(2)));
typedef unsigned int u32x4 __attribute__((ext_vector_type(4)));

#define MFMA(a, b, c) __builtin_amdgcn_mfma_f32_16x16x32_bf16(a, b, c, 0, 0, 0)

// ws layout (bytes)
#define WS_WX1 0         // 32768: Wx1 bf16 frags
#define WS_WX2 32768     // 16384: Wx2 frags
#define WS_WP1 49152     // 16384: Wp1 frags
#define WS_MISC 65536    // 2048: biases etc (floats)
#define WS_OFF 68608     // off[100128] int = 400512 B (CSR offsets, padded)
#define WS_CNT 469504    // counts/cursor[100000] int = 400000 B (aliased)
#define WS_SREC 917504   // u32[EDGES] = 4 MB packed sorted records (lc<<17|r)
#define WS_POSW 8917504  // float4[NODES] = 1.6 MB {pos.xyz, w_pos} per node
#define WS_XB 10517504   // bf16[NODES][64] = 12.8 MB x pre-converted to bf16
// scan temporaries alias the srec region (they die before scatter writes srec):
#define WS_TMP WS_SREC                 // int[100352] inclusive per-block scans
#define WS_BSUM (WS_SREC + 401408)     // int[98] block sums

__device__ __forceinline__ unsigned short f2bf(float f) {
  union { float f; unsigned int u; } c;
  c.f = f;
  unsigned int u = c.u;
  u += 0x7fffu + ((u >> 16) & 1u);
  return (unsigned short)(u >> 16);
}

__device__ __forceinline__ unsigned int pack2bf(float lo, float hi) {
  return (unsigned int)f2bf(lo) | ((unsigned int)f2bf(hi) << 16);
}

// single-instruction RNE pack (same rounding as f2bf); no builtin on gfx950
__device__ __forceinline__ unsigned int cvtpk2bf(float lo, float hi) {
  unsigned int r;
  asm("v_cvt_pk_bf16_f32 %0, %1, %2" : "=v"(r) : "v"(lo), "v"(hi));
  return r;
}

// global -> LDS direct (16B/lane). LDS dest = uniform base + lane*16;
// global src is per-lane (guide m97/m104/m173).
__device__ __forceinline__ void gload16(const void* g, void* l) {
  __builtin_amdgcn_global_load_lds(
      (const __attribute__((address_space(1))) void*)g,
      (__attribute__((address_space(3))) void*)l, 16, 0, 0);
}

__device__ __forceinline__ float fast_silu(float v) {
#if __has_builtin(__builtin_amdgcn_exp2f) && __has_builtin(__builtin_amdgcn_rcpf)
  float e = __builtin_amdgcn_exp2f(-1.44269504088896340736f * v);
  return v * __builtin_amdgcn_rcpf(1.0f + e);
#else
  return v / (1.0f + __expf(-v));
#endif
}

// DPP cross-lane within 16-lane rows. MUST be called unconditionally in
// straight-line code (convergent ops).
template <int CTRL>
__device__ __forceinline__ int dpp_i(int v) {
  return __builtin_amdgcn_update_dpp(0, v, CTRL, 0xf, 0xf, true);
}
template <int CTRL>
__device__ __forceinline__ float dpp_f(float v) {
  return __builtin_bit_cast(float, dpp_i<CTRL>(__builtin_bit_cast(int, v)));
}

// Segmented inclusive prefix-sum across nn (16-lane row), segments = runs of
// equal sorted keys; masks m1..m8 from unconditional key equality at d=1,2,4,8.
__device__ __forceinline__ float segscan(float v, bool m1, bool m2, bool m4, bool m8) {
  float t;
  t = dpp_f<0x111>(v); v += m1 ? t : 0.f;
  t = dpp_f<0x112>(v); v += m2 ? t : 0.f;
  t = dpp_f<0x114>(v); v += m4 ? t : 0.f;
  t = dpp_f<0x118>(v); v += m8 ? t : 0.f;
  return v;
}

__device__ __forceinline__ void lds_add(float* p, float v) {
  __hip_atomic_fetch_add(p, v, __ATOMIC_RELAXED, __HIP_MEMORY_SCOPE_WORKGROUP);
}

// prep also zero-inits counts (wpos's folded hist runs after prep)
__global__ __launch_bounds__(256) void prep_kernel(
    const float* __restrict__ Wx1, const float* __restrict__ Wx2,
    const float* __restrict__ Wp1, const float* __restrict__ bx1,
    const float* __restrict__ bx2, const float* __restrict__ bp1,
    const float* __restrict__ Wp2, const float* __restrict__ bp2,
    unsigned char* __restrict__ ws) {
  const int t = blockIdx.x * 256 + threadIdx.x;
  const int nthr = gridDim.x * 256;

  int* counts = (int*)(ws + WS_CNT);
  for (int i = t; i < NODES; i += nthr) counts[i] = 0;

  for (int task = t; task < 2048; task += nthr) {  // Wx1[0:128][0:128]
    const int n = task & 127;
    const int kb = task >> 7;
    const int k0 = kb << 3;
    unsigned int d[4];
#pragma unroll
    for (int i = 0; i < 4; ++i)
      d[i] = pack2bf(Wx1[(k0 + 2 * i) * 128 + n], Wx1[(k0 + 2 * i + 1) * 128 + n]);
    const int lane = ((kb & 3) << 4) | (n & 15);
    const int frag = ((kb >> 2) << 3) | (n >> 4);
    *(uint4*)(ws + WS_WX1 + ((size_t)(frag * 64 + lane) << 4)) =
        make_uint4(d[0], d[1], d[2], d[3]);
  }
  for (int task = t; task < 1024; task += nthr) {  // Wx2[0:128][0:64]
    const int n = task & 63;
    const int kb = task >> 6;
    const int k0 = kb << 3;
    unsigned int d[4];
#pragma unroll
    for (int i = 0; i < 4; ++i)
      d[i] = pack2bf(Wx2[(k0 + 2 * i) * 64 + n], Wx2[(k0 + 2 * i + 1) * 64 + n]);
    const int lane = ((kb & 3) << 4) | (n & 15);
    const int frag = ((kb >> 2) << 2) | (n >> 4);
    *(uint4*)(ws + WS_WX2 + ((size_t)(frag * 64 + lane) << 4)) =
        make_uint4(d[0], d[1], d[2], d[3]);
  }
  for (int task = t; task < 1024; task += nthr) {  // Wp1[0:64][0:128]
    const int n = task & 127;
    const int kb = task >> 7;
    const int k0 = kb << 3;
    unsigned int d[4];
#pragma unroll
    for (int i = 0; i < 4; ++i)
      d[i] = pack2bf(Wp1[(k0 + 2 * i) * 128 + n], Wp1[(k0 + 2 * i + 1) * 128 + n]);
    const int lane = ((kb & 3) << 4) | (n & 15);
    const int frag = ((kb >> 2) << 3) | (n >> 4);
    *(uint4*)(ws + WS_WP1 + ((size_t)(frag * 64 + lane) << 4)) =
        make_uint4(d[0], d[1], d[2], d[3]);
  }
  float* misc = (float*)(ws + WS_MISC);
  for (int i = t; i < 128; i += nthr) misc[i] = bx1[i];
  for (int i = t; i < 64; i += nthr) misc[128 + i] = bx2[i];
  for (int i = t; i < 128; i += nthr) misc[192 + i] = bp1[i];
  for (int i = t; i < 128; i += nthr) misc[320 + i] = Wp2[i];
  if (t == 0) misc[448] = bp2[0];
  for (int i = t; i < 128; i += nthr) misc[456 + i] = Wx1[128 * 128 + i];
}

// ---- per-NODE phi_pos precompute + x -> bf16 + folded hist ----
__global__ __launch_bounds__(256) void wpos_kernel(
    const float* __restrict__ x, const float* __restrict__ pos,
    const int* __restrict__ ei, unsigned char* __restrict__ ws) {
  __shared__ float sX[128 * 68];  // 34816 B, stride 68 (16B-aligned, low conflict)

  const uint4* wp1f = (const uint4*)(ws + WS_WP1);
  const float* misc = (const float*)(ws + WS_MISC);
  float* posw = (float*)(ws + WS_POSW);
  unsigned char* xb = ws + WS_XB;
  int* counts = (int*)(ws + WS_CNT);

  const int tid = threadIdx.x;
  const int lane = tid & 63;
  const int wave = tid >> 6;
  const int q = lane >> 4;
  const int nn = lane & 15;
  const int B0 = blockIdx.x * 128;
  const int nvalid = (NODES - B0 < 128) ? (NODES - B0) : 128;

  // stage x[B0..B0+128) coalesced: 2048 float4s, 8 per thread
#pragma unroll
  for (int k = 0; k < 8; ++k) {
    const int fidx = tid + k * 256;  // float4 index
    const int row = fidx >> 4, c4 = fidx & 15;
    float4 v = make_float4(0.f, 0.f, 0.f, 0.f);
    if (row < nvalid) v = *(const float4*)(x + ((size_t)(B0 + row)) * 64 + c4 * 4);
    *(float4*)(sX + row * 68 + c4 * 4) = v;
  }
  __syncthreads();

  // xb bf16 copy: 4096 u32 outputs, 16 per thread, coalesced
#pragma unroll
  for (int k = 0; k < 16; ++k) {
    const int pidx = tid + k * 256;           // u32 index
    const int row = pidx >> 5, cp = pidx & 31;  // 32 u32 per 128B row
    if (B0 + row < NODES)
      *(unsigned int*)(xb + ((size_t)(B0 + row)) * 128 + cp * 4) =
          cvtpk2bf(sX[row * 68 + cp * 2], sX[row * 68 + cp * 2 + 1]);
  }

  // B-frags from LDS (invalid rows zero-filled; posw write is guarded)
  const int base = wave * 32;  // node-local base for this wave
  short8 bf[2][2];
#pragma unroll
  for (int m = 0; m < 2; ++m) {
    const int nl = base + m * 16 + nn;
#pragma unroll
    for (int kt = 0; kt < 2; ++kt) {
      const float4 a = *(const float4*)(sX + nl * 68 + kt * 32 + q * 8);
      const float4 b = *(const float4*)(sX + nl * 68 + kt * 32 + q * 8 + 4);
      u32x4 d;
      d[0] = cvtpk2bf(a.x, a.y);
      d[1] = cvtpk2bf(a.z, a.w);
      d[2] = cvtpk2bf(b.x, b.y);
      d[3] = cvtpk2bf(b.z, b.w);
      bf[m][kt] = __builtin_bit_cast(short8, d);
    }
  }

  const floatx4 fzero = {0.f, 0.f, 0.f, 0.f};
  floatx4 accp[2][8];
#pragma unroll
  for (int m = 0; m < 2; ++m)
#pragma unroll
    for (int j = 0; j < 8; ++j) accp[m][j] = fzero;
#pragma unroll 1
  for (int kt = 0; kt < 2; ++kt) {
#pragma unroll
    for (int jt = 0; jt < 8; ++jt) {
      const short8 a = __builtin_bit_cast(short8, wp1f[(kt * 8 + jt) * 64 + lane]);
      accp[0][jt] = MFMA(a, bf[0][kt], accp[0][jt]);
      accp[1][jt] = MFMA(a, bf[1][kt], accp[1][jt]);
    }
  }
#pragma unroll
  for (int m = 0; m < 2; ++m) {
    float s = 0.f;
#pragma unroll
    for (int jt = 0; jt < 8; ++jt) {
      const float4 bp = *(const float4*)(misc + 192 + jt * 16 + q * 4);
      const float4 wp = *(const float4*)(misc + 320 + jt * 16 + q * 4);
      s += fast_silu(accp[m][jt][0] + bp.x) * wp.x;
      s += fast_silu(accp[m][jt][1] + bp.y) * wp.y;
      s += fast_silu(accp[m][jt][2] + bp.z) * wp.z;
      s += fast_silu(accp[m][jt][3] + bp.w) * wp.w;
    }
    s += __shfl_xor(s, 16);
    s += __shfl_xor(s, 32);
    const int node = B0 + base + m * 16 + nn;
    if (q == 0 && node < NODES) {
      float4 o;
      o.x = pos[3 * node + 0];
      o.y = pos[3 * node + 1];
      o.z = pos[3 * node + 2];
      o.w = s + misc[448];
      *(float4*)(posw + 4 * (size_t)node) = o;
    }
  }

  // ---- folded hist (grid-stride; counts zeroed by prep)
  const int gsz = gridDim.x * 256;
  for (int t = blockIdx.x * 256 + tid; t < EDGES; t += gsz) {
    int c = __builtin_nontemporal_load(ei + EDGES + t);
    c = (c < 0) ? 0 : ((c >= NODES) ? NODES - 1 : c);
    atomicAdd(&counts[c], 1);
  }
}

#define SCB 98  // blocks of 1024: 98*1024 = 100352 >= NODES+128

__global__ __launch_bounds__(1024) void scan1_kernel(const int* __restrict__ counts,
                                                     int* __restrict__ tmp,
                                                     int* __restrict__ bsum) {
  __shared__ int part[1024];
  const int t = threadIdx.x;
  const int i = blockIdx.x * 1024 + t;
  int v = (i < NODES) ? counts[i] : 0;
  part[t] = v;
  __syncthreads();
  for (int d = 1; d < 1024; d <<= 1) {
    int u = 0;
    if (t >= d) u = part[t - d];
    __syncthreads();
    if (t >= d) part[t] += u;
    __syncthreads();
  }
  tmp[i] = part[t];  // inclusive scan within block
  if (t == 1023) bsum[blockIdx.x] = part[1023];
}

// scan2 merged in — each block re-scans the 98 block sums in LDS.
__global__ __launch_bounds__(1024) void scan3_kernel(const int* __restrict__ counts,
                                                     const int* __restrict__ tmp,
                                                     const int* __restrict__ bsum,
                                                     int* __restrict__ off,
                                                     int* __restrict__ cursor) {
  __shared__ int sb[128];
  const int t = threadIdx.x;
  if (t < 128) sb[t] = (t < SCB) ? bsum[t] : 0;
  __syncthreads();
  for (int d = 1; d < 128; d <<= 1) {
    int u = 0;
    if (t >= d && t < 128) u = sb[t - d];
    __syncthreads();
    if (t >= d && t < 128) sb[t] += u;
    __syncthreads();
  }
  const int bx = (blockIdx.x == 0) ? 0 : sb[blockIdx.x - 1];  // exclusive
  const int i = blockIdx.x * 1024 + t;
  if (i < NODES) {
    const int cn = counts[i];  // read before cursor write (aliased with counts)
    const int o = bx + tmp[i] - cn;
    off[i] = o;
    cursor[i] = o;
  } else if (i < NODES + 128) {
    off[i] = EDGES;
  }
}

// packed record — lc = c & 31 (NB=32; block base is (c>>5)*32), r < 2^17.
__global__ __launch_bounds__(256) void scatter_kernel(const int* __restrict__ ei,
                                                      int* __restrict__ cursor,
                                                      unsigned int* __restrict__ srec) {
  const int t = blockIdx.x * 256 + threadIdx.x;
  if (t < EDGES) {
    int r = __builtin_nontemporal_load(ei + t);
    int c = __builtin_nontemporal_load(ei + EDGES + t);
    r = (r < 0) ? 0 : ((r >= NODES) ? NODES - 1 : r);
    c = (c < 0) ? 0 : ((c >= NODES) ? NODES - 1 : c);
    const int p = atomicAdd(&cursor[c], 1);
    __builtin_nontemporal_store(((unsigned)(c & 31) << 17) | (unsigned)r, srec + p);
  }
}

// ---- main: node-centric, zero global atomics, zero in-loop barriers ----
// Frozen at the R17/R19 structure (proven 218-220 µs, spill-free):
// cols block-local in xbCol (swizzled, staged once); rows via global_load_lds
// from bf16 xb; vmcnt(1)+sched_barrier guards gload->ds_read; F/G per-m with
// h streamed to sH and 4 NAMED GEMM2 accumulators (rule #20); all in-loop
// LDS slots wave-own. R18's occupancy-via-serialization regressed; reverted.
// R20's fused spin-wait scan removed (two-kernel scan is both proven AND
// measured-faster — R18 pre-chain 208 µs vs R19 fused 232 µs).
// R22 = byte-identical resubmit of R21 (all components hardware-proven;
// consecutive container failures diagnosed as infra, not kernel).
__global__ __launch_bounds__(256, 3) void node_kernel(
    const unsigned char* __restrict__ ws, float* __restrict__ out) {
  __shared__ uint4 sG[1024];                      // 16 KB row-gather frags
  __shared__ uint4 sH[1024];                      // 16 KB h frags (4 rows/wave)
  __shared__ __align__(16) float sAccX[NB * 68];  // 8.7 KB; cols 64..66 = pos
  __shared__ unsigned char xbCol[4096];           // 4 KB block col features
  __shared__ float4 sPosC[NB];                    // 512 B block col posw
  __shared__ unsigned int sRC[ET];                // 512 B packed (lc<<17|r)
  __shared__ float sW[ET];                        // 512 B
  __shared__ float sRel[ET * 3];                  // 1.5 KB
  __shared__ float sDist[ET];                     // 512 B

  const int tid = threadIdx.x;
  const int lane = tid & 63;
  const int wave = tid >> 6;
  const int q = lane >> 4;
  const int nn = lane & 15;
  const int base = blockIdx.x * NB;
  const int et0 = wave * 2;
  const int W32 = wave * 32;

  const int* off = (const int*)(ws + WS_OFF);
  const unsigned int* srec = (const unsigned int*)(ws + WS_SREC);
  const uint4* wx1f = (const uint4*)(ws + WS_WX1);
  const uint4* wx2f = (const uint4*)(ws + WS_WX2);
  const float* misc = (const float*)(ws + WS_MISC);
  const float* posw = (const float*)(ws + WS_POSW);
  const unsigned char* xb = ws + WS_XB;

  const int e0 = off[base];
  const int e1 = off[base + NB];

  // ---- block staging: xbCol (swizzled), sPosC, zero sAccX
  {
    const int row = tid >> 3;
    const int o = (tid & 7) << 4;
    const uint4 v = *(const uint4*)(xb + (size_t)(base + row) * 128 + o);
    *(uint4*)(xbCol + (row << 7) + (o ^ ((row & 7) << 4))) = v;
  }
  if (tid < NB) sPosC[tid] = *(const float4*)(posw + 4 * (size_t)(base + tid));
  for (int i = tid; i < NB * 68; i += 256) sAccX[i] = 0.f;

  // ---- prologue: tile-0 record + posw[r]
  unsigned int prec = 0;
  if (lane < 32) {
    int e = e0 + W32 + lane;
    e = e < EDGES ? e : EDGES - 1;
    prec = srec[e];
  }
  unsigned int rec0 = __shfl(prec, nn);
  unsigned int rec1 = __shfl(prec, 16 + nn);
  float4 pR = {0.f, 0.f, 0.f, 0.f};
  if (lane < 32) pR = *(const float4*)(posw + 4 * (size_t)(prec & 0x1FFFFu));
  __syncthreads();  // staging visible; also drains vmcnt (prec/pR done)

  // ---- issue tile-0 row gloads (stay in flight into iter 0)
  {
    const int ko = (lane >> 4) << 4;
#pragma unroll
    for (int mm = 0; mm < 2; ++mm) {
      const unsigned int rr = mm ? rec1 : rec0;
      const unsigned char* g0 = xb + ((size_t)(rr & 0x1FFFFu) << 7) + ko;
      gload16(g0, &sG[((et0 + mm) * 2 + 0) * 64]);
      gload16(g0 + 64, &sG[((et0 + mm) * 2 + 1) * 64]);
    }
  }

  const floatx4 fzero = {0.f, 0.f, 0.f, 0.f};

#pragma unroll 1
  for (int t0 = e0; t0 < e1; t0 += ET) {
    // ---- A: wave-own metadata -> LDS (pC from sPosC; pR prefetched)
    if (lane < 32) {
      const int j = W32 + lane;
      const float4 pc = sPosC[prec >> 17];
      const float r0 = pR.x - pc.x;
      const float r1 = pR.y - pc.y;
      const float r2 = pR.z - pc.z;
      sRC[j] = prec;
      sW[j] = pR.w;
      sRel[3 * j + 0] = r0;
      sRel[3 * j + 1] = r1;
      sRel[3 * j + 2] = r2;
      sDist[j] = r0 * r0 + r1 * r1 + r2 * r2;
    }

    // ---- B: issue next tile's srec
    unsigned int rcN = 0;
    if (lane < 32) {
      int e = t0 + ET + W32 + lane;
      e = e < EDGES ? e : EDGES - 1;
      rcN = srec[e];
    }

    // ---- C: row gloads for THIS tile landed (rcN still in flight)
    asm volatile("s_waitcnt vmcnt(1)" ::: "memory");
    __builtin_amdgcn_sched_barrier(0);

    // ---- D: GEMM1 — kt0,1 B from sG (gload rows); kt2,3 B from xbCol
    floatx4 acc1[2][8];
#pragma unroll
    for (int m = 0; m < 2; ++m)
#pragma unroll
      for (int j = 0; j < 8; ++j) acc1[m][j] = fzero;
#pragma unroll 1
    for (int kt = 0; kt < 2; ++kt) {
      const short8 b0 = __builtin_bit_cast(short8, sG[((et0 + 0) * 2 + kt) * 64 + lane]);
      const short8 b1 = __builtin_bit_cast(short8, sG[((et0 + 1) * 2 + kt) * 64 + lane]);
#pragma unroll
      for (int jt = 0; jt < 8; ++jt) {
        const short8 a = __builtin_bit_cast(short8, wx1f[(kt * 8 + jt) * 64 + lane]);
        acc1[0][jt] = MFMA(a, b0, acc1[0][jt]);
        acc1[1][jt] = MFMA(a, b1, acc1[1][jt]);
      }
    }
    {
      const int lc0 = (int)(rec0 >> 17);
      const int lc1 = (int)(rec1 >> 17);
#pragma unroll 1
      for (int kt = 2; kt < 4; ++kt) {
        const int o = ((kt & 1) << 6) | ((lane >> 4) << 4);
        const short8 b0 =
            *(const short8*)(xbCol + (lc0 << 7) + (o ^ ((lc0 & 7) << 4)));
        const short8 b1 =
            *(const short8*)(xbCol + (lc1 << 7) + (o ^ ((lc1 & 7) << 4)));
#pragma unroll
        for (int jt = 0; jt < 8; ++jt) {
          const short8 a = __builtin_bit_cast(short8, wx1f[(kt * 8 + jt) * 64 + lane]);
          acc1[0][jt] = MFMA(a, b0, acc1[0][jt]);
          acc1[1][jt] = MFMA(a, b1, acc1[1][jt]);
        }
      }
    }

    // ---- E: next-tile prefetch (sG rows free; cover = F+G)
    __builtin_amdgcn_sched_barrier(0);
    {
      if (lane < 32) pR = *(const float4*)(posw + 4 * (size_t)(rcN & 0x1FFFFu));
      const unsigned int rec0n = __shfl(rcN, nn);
      const unsigned int rec1n = __shfl(rcN, 16 + nn);
      const int ko = (lane >> 4) << 4;
#pragma unroll
      for (int mm = 0; mm < 2; ++mm) {
        const unsigned int rr = mm ? rec1n : rec0n;
        const unsigned char* g0 = xb + ((size_t)(rr & 0x1FFFFu) << 7) + ko;
        gload16(g0, &sG[((et0 + mm) * 2 + 0) * 64]);
        gload16(g0 + 64, &sG[((et0 + mm) * 2 + 1) * 64]);
      }
      rec0 = rec0n;
      rec1 = rec1n;
      prec = rcN;
    }

    // ---- F+G per m: epi1(m)->sH direct, GEMM2(m) named accs, scatter(m)
#pragma unroll
    for (int m = 0; m < 2; ++m) {
      const int el = (et0 + m) * 16 + nn;
      const float dist = sDist[el];
      // epi1(m): 8 static jt, stream h straight to sH rows wave*4+kt2
#pragma unroll
      for (int jt = 0; jt < 8; ++jt) {
        const float4 bx = *(const float4*)(misc + 0 + jt * 16 + q * 4);
        const float4 wd = *(const float4*)(misc + 456 + jt * 16 + q * 4);
        const unsigned int h01 = cvtpk2bf(fast_silu(acc1[m][jt][0] + bx.x + dist * wd.x),
                                          fast_silu(acc1[m][jt][1] + bx.y + dist * wd.y));
        const unsigned int h23 = cvtpk2bf(fast_silu(acc1[m][jt][2] + bx.z + dist * wd.z),
                                          fast_silu(acc1[m][jt][3] + bx.w + dist * wd.w));
        const int j0 = jt * 16 + q * 4;  // 0..127
        const int kt2 = j0 >> 5;
        const int lane2 = (((j0 & 31) >> 3) << 4) | nn;
        const int byteoff = (j0 & 7) << 1;
        uint2* dst = (uint2*)((char*)sH +
                              (((size_t)((wave * 4 + kt2) * 64 + lane2)) << 4) + byteoff);
        *dst = make_uint2(h01, h23);
      }
      // GEMM2(m): 4 named accumulators (16 AGPR)
      floatx4 a20 = fzero, a21 = fzero, a22 = fzero, a23 = fzero;
#pragma unroll 1
      for (int kt = 0; kt < 4; ++kt) {
        const short8 b = __builtin_bit_cast(short8, sH[(wave * 4 + kt) * 64 + lane]);
        a20 = MFMA(__builtin_bit_cast(short8, wx2f[(kt * 4 + 0) * 64 + lane]), b, a20);
        a21 = MFMA(__builtin_bit_cast(short8, wx2f[(kt * 4 + 1) * 64 + lane]), b, a21);
        a22 = MFMA(__builtin_bit_cast(short8, wx2f[(kt * 4 + 2) * 64 + lane]), b, a22);
        a23 = MFMA(__builtin_bit_cast(short8, wx2f[(kt * 4 + 3) * 64 + lane]), b, a23);
      }
      // scatter(m): masks + pos + x-features
      const bool vE = (t0 + el) < e1;
      int lcv = (int)(sRC[el] >> 17);
      if (!vE) lcv = -1 - nn;  // singleton segments for invalid lanes
      // unconditional DPPs (convergent!) then bitwise combines:
      const int k1 = dpp_i<0x111>(lcv);
      const int k2 = dpp_i<0x112>(lcv);
      const int k4 = dpp_i<0x114>(lcv);
      const int k8 = dpp_i<0x118>(lcv);
      const int kn = dpp_i<0x101>(lcv);
      const bool m1 = (nn >= 1) & (k1 == lcv);
      const bool m2 = (nn >= 2) & (k2 == lcv);
      const bool m4 = (nn >= 4) & (k4 == lcv);
      const bool m8 = (nn >= 8) & (k8 == lcv);
      const bool tail = vE & ((nn == 15) | (kn != lcv));

      // pos update (w precomputed per node)
      const float wv = sW[el];
      float p0 = segscan(wv * sRel[3 * el + 0], m1, m2, m4, m8);
      float p1 = segscan(wv * sRel[3 * el + 1], m1, m2, m4, m8);
      float p2 = segscan(wv * sRel[3 * el + 2], m1, m2, m4, m8);
      if (tail && q == 0) {
        float* ap = sAccX + lcv * 68 + 64;  // pos acc lives in the pad
        lds_add(ap + 0, p0);
        lds_add(ap + 1, p1);
        lds_add(ap + 2, p2);
      }
      {
        const float4 b2 = *(const float4*)(misc + 128 + 0 * 16 + q * 4);
        float v0 = segscan(a20[0] + b2.x, m1, m2, m4, m8);
        float v1 = segscan(a20[1] + b2.y, m1, m2, m4, m8);
        float v2 = segscan(a20[2] + b2.z, m1, m2, m4, m8);
        float v3 = segscan(a20[3] + b2.w, m1, m2, m4, m8);
        if (tail) {
          float* arow = sAccX + lcv * 68 + q * 4;
          lds_add(arow + 0, v0);
          lds_add(arow + 1, v1);
          lds_add(arow + 2, v2);
          lds_add(arow + 3, v3);
        }
      }
      {
        const float4 b2 = *(const float4*)(misc + 128 + 1 * 16 + q * 4);
        float v0 = segscan(a21[0] + b2.x, m1, m2, m4, m8);
        float v1 = segscan(a21[1] + b2.y, m1, m2, m4, m8);
        float v2 = segscan(a21[2] + b2.z, m1, m2, m4, m8);
        float v3 = segscan(a21[3] + b2.w, m1, m2, m4, m8);
        if (tail) {
          float* arow = sAccX + lcv * 68 + 16 + q * 4;
          lds_add(arow + 0, v0);
          lds_add(arow + 1, v1);
          lds_add(arow + 2, v2);
          lds_add(arow + 3, v3);
        }
      }
      {
        const float4 b2 = *(const float4*)(misc + 128 + 2 * 16 + q * 4);
        float v0 = segscan(a22[0] + b2.x, m1, m2, m4, m8);
        float v1 = segscan(a22[1] + b2.y, m1, m2, m4, m8);
        float v2 = segscan(a22[2] + b2.z, m1, m2, m4, m8);
        float v3 = segscan(a22[3] + b2.w, m1, m2, m4, m8);
        if (tail) {
          float* arow = sAccX + lcv * 68 + 32 + q * 4;
          lds_add(arow + 0, v0);
          lds_add(arow + 1, v1);
          lds_add(arow + 2, v2);
          lds_add(arow + 3, v3);
        }
      }
      {
        const float4 b2 = *(const float4*)(misc + 128 + 3 * 16 + q * 4);
        float v0 = segscan(a23[0] + b2.x, m1, m2, m4, m8);
        float v1 = segscan(a23[1] + b2.y, m1, m2, m4, m8);
        float v2 = segscan(a23[2] + b2.z, m1, m2, m4, m8);
        float v3 = segscan(a23[3] + b2.w, m1, m2, m4, m8);
        if (tail) {
          float* arow = sAccX + lcv * 68 + 48 + q * 4;
          lds_add(arow + 0, v0);
          lds_add(arow + 1, v1);
          lds_add(arow + 2, v2);
          lds_add(arow + 3, v3);
        }
      }
    }
    // no end-of-loop barrier: all in-loop LDS arrays are wave-own slots.
  }
  __syncthreads();  // all waves' LDS-atomic accumulates done

  // ---- final coalesced stores (no global atomics); NODES % NB == 0
  {
    const int n = base + (tid >> 3);
    const int c0 = (tid & 7) * 8;
    float* orow = out + (size_t)n * 64 + c0;
    const float* arow = sAccX + (tid >> 3) * 68 + c0;
    *(float4*)(orow + 0) = *(const float4*)(arow + 0);
    *(float4*)(orow + 4) = *(const float4*)(arow + 4);
    if (tid < NB * 3)
      out[(size_t)NODES * 64 + base * 3 + tid] = sAccX[(tid / 3) * 68 + 64 + (tid % 3)];
  }
}

extern "C" void kernel_launch(void* const* d_in, const int* in_sizes, int n_in,
                              void* d_out, int out_size, void* d_ws, size_t ws_size,
                              hipStream_t stream) {
  (void)in_sizes; (void)n_in; (void)ws_size; (void)out_size;
  const float* x = (const float*)d_in[0];
  const float* pos = (const float*)d_in[1];
  const int* ei = (const int*)d_in[2];
  const float* Wx1 = (const float*)d_in[3];
  const float* bx1 = (const float*)d_in[4];
  const float* Wx2 = (const float*)d_in[5];
  const float* bx2 = (const float*)d_in[6];
  const float* Wp1 = (const float*)d_in[7];
  const float* bp1 = (const float*)d_in[8];
  const float* Wp2 = (const float*)d_in[9];
  const float* bp2 = (const float*)d_in[10];
  float* out = (float*)d_out;
  unsigned char* ws = (unsigned char*)d_ws;

  int* counts = (int*)(ws + WS_CNT);   // aliased with cursor (scan3 rewrites)
  int* cursor = (int*)(ws + WS_CNT);
  int* off = (int*)(ws + WS_OFF);
  int* tmp = (int*)(ws + WS_TMP);      // aliased with srec (dies before scatter)
  int* bsum = (int*)(ws + WS_BSUM);
  unsigned int* srec = (unsigned int*)(ws + WS_SREC);

  prep_kernel<<<64, 256, 0, stream>>>(Wx1, Wx2, Wp1, bx1, bx2, bp1, Wp2, bp2, ws);
  wpos_kernel<<<NBW, 256, 0, stream>>>(x, pos, ei, ws);  // + folded hist
  scan1_kernel<<<SCB, 1024, 0, stream>>>(counts, tmp, bsum);
  scan3_kernel<<<SCB, 1024, 0, stream>>>(counts, tmp, bsum, off, cursor);
  const int eb = (EDGES + 255) / 256;
  scatter_kernel<<<eb, 256, 0, stream>>>(ei, cursor, srec);
  node_kernel<<<NBLK, 256, 0, stream>>>(ws, out);
}

// Round 14
// 390.666 us; speedup vs baseline: 1.2374x; 1.1142x over previous
//
#include <hip/hip_runtime.h>

#define EDGES 1000000
#define NODES 100000
#define ET 128   // edges per tile (4 waves x 32)
#define NB 32    // nodes per block (node_kernel); 100000 % 32 == 0
#define NBLK (NODES / NB)             // 3125
#define NBW ((NODES + 127) / 128)     // 782 wpos blocks

typedef short short8 __attribute__((ext_vector_type(8)));
typedef float floatx4 __attribute__((ext_vector_type(4)));
typedef unsigned int u32x2 __attribute__((ext_vector_type(2)));
typedef unsigned int u32x4 __attribute__((ext_vector_type(4)));

#define MFMA(a, b, c) __builtin_amdgcn_mfma_f32_16x16x32_bf16(a, b, c, 0, 0, 0)

// ws layout (bytes)
#define WS_WX1 0         // 32768: Wx1 bf16 frags
#define WS_WX2 32768     // 16384: Wx2 frags
#define WS_WP1 49152     // 16384: Wp1 frags
#define WS_MISC 65536    // 2048: biases etc (floats)
#define WS_OFF 68608     // off[100128] int = 400512 B (CSR offsets, padded)
#define WS_CNT 469504    // counts[100000] int = 400000 B
#define WS_SREC 917504   // u32[EDGES] = 4 MB packed sorted records (lc<<17|r)
#define WS_PLOC 4917504  // u32[EDGES] = 4 MB per-edge rank within its col
#define WS_POSW 8917504  // float4[NODES] = 1.6 MB {pos.xyz, w_pos} per node
#define WS_XB 10517504   // bf16[NODES][64] = 12.8 MB x pre-converted to bf16
// scan temporaries alias the srec region (they die before scatter writes srec):
#define WS_TMP WS_SREC                 // int[100352] inclusive per-block scans
#define WS_BSUM (WS_SREC + 401408)     // int[98] block sums

__device__ __forceinline__ unsigned short f2bf(float f) {
  union { float f; unsigned int u; } c;
  c.f = f;
  unsigned int u = c.u;
  u += 0x7fffu + ((u >> 16) & 1u);
  return (unsigned short)(u >> 16);
}

__device__ __forceinline__ unsigned int pack2bf(float lo, float hi) {
  return (unsigned int)f2bf(lo) | ((unsigned int)f2bf(hi) << 16);
}

// single-instruction RNE pack (same rounding as f2bf); no builtin on gfx950
__device__ __forceinline__ unsigned int cvtpk2bf(float lo, float hi) {
  unsigned int r;
  asm("v_cvt_pk_bf16_f32 %0, %1, %2" : "=v"(r) : "v"(lo), "v"(hi));
  return r;
}

// global -> LDS direct (16B/lane). LDS dest = uniform base + lane*16;
// global src is per-lane (guide m97/m104/m173).
__device__ __forceinline__ void gload16(const void* g, void* l) {
  __builtin_amdgcn_global_load_lds(
      (const __attribute__((address_space(1))) void*)g,
      (__attribute__((address_space(3))) void*)l, 16, 0, 0);
}

__device__ __forceinline__ float fast_silu(float v) {
#if __has_builtin(__builtin_amdgcn_exp2f) && __has_builtin(__builtin_amdgcn_rcpf)
  float e = __builtin_amdgcn_exp2f(-1.44269504088896340736f * v);
  return v * __builtin_amdgcn_rcpf(1.0f + e);
#else
  return v / (1.0f + __expf(-v));
#endif
}

// DPP cross-lane within 16-lane rows. MUST be called unconditionally in
// straight-line code (convergent ops).
template <int CTRL>
__device__ __forceinline__ int dpp_i(int v) {
  return __builtin_amdgcn_update_dpp(0, v, CTRL, 0xf, 0xf, true);
}
template <int CTRL>
__device__ __forceinline__ float dpp_f(float v) {
  return __builtin_bit_cast(float, dpp_i<CTRL>(__builtin_bit_cast(int, v)));
}

// Segmented inclusive prefix-sum across nn (16-lane row), segments = runs of
// equal sorted keys; masks m1..m8 from unconditional key equality at d=1,2,4,8.
__device__ __forceinline__ float segscan(float v, bool m1, bool m2, bool m4, bool m8) {
  float t;
  t = dpp_f<0x111>(v); v += m1 ? t : 0.f;
  t = dpp_f<0x112>(v); v += m2 ? t : 0.f;
  t = dpp_f<0x114>(v); v += m4 ? t : 0.f;
  t = dpp_f<0x118>(v); v += m8 ? t : 0.f;
  return v;
}

__device__ __forceinline__ void lds_add(float* p, float v) {
  __hip_atomic_fetch_add(p, v, __ATOMIC_RELAXED, __HIP_MEMORY_SCOPE_WORKGROUP);
}

// prep also zero-inits counts (wpos's folded hist runs after prep)
__global__ __launch_bounds__(256) void prep_kernel(
    const float* __restrict__ Wx1, const float* __restrict__ Wx2,
    const float* __restrict__ Wp1, const float* __restrict__ bx1,
    const float* __restrict__ bx2, const float* __restrict__ bp1,
    const float* __restrict__ Wp2, const float* __restrict__ bp2,
    unsigned char* __restrict__ ws) {
  const int t = blockIdx.x * 256 + threadIdx.x;
  const int nthr = gridDim.x * 256;

  int* counts = (int*)(ws + WS_CNT);
  for (int i = t; i < NODES; i += nthr) counts[i] = 0;

  for (int task = t; task < 2048; task += nthr) {  // Wx1[0:128][0:128]
    const int n = task & 127;
    const int kb = task >> 7;
    const int k0 = kb << 3;
    unsigned int d[4];
#pragma unroll
    for (int i = 0; i < 4; ++i)
      d[i] = pack2bf(Wx1[(k0 + 2 * i) * 128 + n], Wx1[(k0 + 2 * i + 1) * 128 + n]);
    const int lane = ((kb & 3) << 4) | (n & 15);
    const int frag = ((kb >> 2) << 3) | (n >> 4);
    *(uint4*)(ws + WS_WX1 + ((size_t)(frag * 64 + lane) << 4)) =
        make_uint4(d[0], d[1], d[2], d[3]);
  }
  for (int task = t; task < 1024; task += nthr) {  // Wx2[0:128][0:64]
    const int n = task & 63;
    const int kb = task >> 6;
    const int k0 = kb << 3;
    unsigned int d[4];
#pragma unroll
    for (int i = 0; i < 4; ++i)
      d[i] = pack2bf(Wx2[(k0 + 2 * i) * 64 + n], Wx2[(k0 + 2 * i + 1) * 64 + n]);
    const int lane = ((kb & 3) << 4) | (n & 15);
    const int frag = ((kb >> 2) << 2) | (n >> 4);
    *(uint4*)(ws + WS_WX2 + ((size_t)(frag * 64 + lane) << 4)) =
        make_uint4(d[0], d[1], d[2], d[3]);
  }
  for (int task = t; task < 1024; task += nthr) {  // Wp1[0:64][0:128]
    const int n = task & 127;
    const int kb = task >> 7;
    const int k0 = kb << 3;
    unsigned int d[4];
#pragma unroll
    for (int i = 0; i < 4; ++i)
      d[i] = pack2bf(Wp1[(k0 + 2 * i) * 128 + n], Wp1[(k0 + 2 * i + 1) * 128 + n]);
    const int lane = ((kb & 3) << 4) | (n & 15);
    const int frag = ((kb >> 2) << 3) | (n >> 4);
    *(uint4*)(ws + WS_WP1 + ((size_t)(frag * 64 + lane) << 4)) =
        make_uint4(d[0], d[1], d[2], d[3]);
  }
  float* misc = (float*)(ws + WS_MISC);
  for (int i = t; i < 128; i += nthr) misc[i] = bx1[i];
  for (int i = t; i < 64; i += nthr) misc[128 + i] = bx2[i];
  for (int i = t; i < 128; i += nthr) misc[192 + i] = bp1[i];
  for (int i = t; i < 128; i += nthr) misc[320 + i] = Wp2[i];
  if (t == 0) misc[448] = bp2[0];
  for (int i = t; i < 128; i += nthr) misc[456 + i] = Wx1[128 * 128 + i];
}

// ---- per-NODE phi_pos precompute + x -> bf16 + folded hist ----
// R23: the hist atomicAdd now KEEPS its return value as p_local[e] (the
// edge's rank within its column, 4 MB gap at WS_PLOC) — scatter_kernel
// then needs no atomics at all (p = off[c] + p_local[e]).
__global__ __launch_bounds__(256) void wpos_kernel(
    const float* __restrict__ x, const float* __restrict__ pos,
    const int* __restrict__ ei, unsigned char* __restrict__ ws) {
  __shared__ float sX[128 * 68];  // 34816 B, stride 68 (16B-aligned, low conflict)

  const uint4* wp1f = (const uint4*)(ws + WS_WP1);
  const float* misc = (const float*)(ws + WS_MISC);
  float* posw = (float*)(ws + WS_POSW);
  unsigned char* xb = ws + WS_XB;
  int* counts = (int*)(ws + WS_CNT);
  int* ploc = (int*)(ws + WS_PLOC);

  const int tid = threadIdx.x;
  const int lane = tid & 63;
  const int wave = tid >> 6;
  const int q = lane >> 4;
  const int nn = lane & 15;
  const int B0 = blockIdx.x * 128;
  const int nvalid = (NODES - B0 < 128) ? (NODES - B0) : 128;

  // stage x[B0..B0+128) coalesced: 2048 float4s, 8 per thread
#pragma unroll
  for (int k = 0; k < 8; ++k) {
    const int fidx = tid + k * 256;  // float4 index
    const int row = fidx >> 4, c4 = fidx & 15;
    float4 v = make_float4(0.f, 0.f, 0.f, 0.f);
    if (row < nvalid) v = *(const float4*)(x + ((size_t)(B0 + row)) * 64 + c4 * 4);
    *(float4*)(sX + row * 68 + c4 * 4) = v;
  }
  __syncthreads();

  // xb bf16 copy: 4096 u32 outputs, 16 per thread, coalesced
#pragma unroll
  for (int k = 0; k < 16; ++k) {
    const int pidx = tid + k * 256;           // u32 index
    const int row = pidx >> 5, cp = pidx & 31;  // 32 u32 per 128B row
    if (B0 + row < NODES)
      *(unsigned int*)(xb + ((size_t)(B0 + row)) * 128 + cp * 4) =
          cvtpk2bf(sX[row * 68 + cp * 2], sX[row * 68 + cp * 2 + 1]);
  }

  // B-frags from LDS (invalid rows zero-filled; posw write is guarded)
  const int base = wave * 32;  // node-local base for this wave
  short8 bf[2][2];
#pragma unroll
  for (int m = 0; m < 2; ++m) {
    const int nl = base + m * 16 + nn;
#pragma unroll
    for (int kt = 0; kt < 2; ++kt) {
      const float4 a = *(const float4*)(sX + nl * 68 + kt * 32 + q * 8);
      const float4 b = *(const float4*)(sX + nl * 68 + kt * 32 + q * 8 + 4);
      u32x4 d;
      d[0] = cvtpk2bf(a.x, a.y);
      d[1] = cvtpk2bf(a.z, a.w);
      d[2] = cvtpk2bf(b.x, b.y);
      d[3] = cvtpk2bf(b.z, b.w);
      bf[m][kt] = __builtin_bit_cast(short8, d);
    }
  }

  const floatx4 fzero = {0.f, 0.f, 0.f, 0.f};
  floatx4 accp[2][8];
#pragma unroll
  for (int m = 0; m < 2; ++m)
#pragma unroll
    for (int j = 0; j < 8; ++j) accp[m][j] = fzero;
#pragma unroll 1
  for (int kt = 0; kt < 2; ++kt) {
#pragma unroll
    for (int jt = 0; jt < 8; ++jt) {
      const short8 a = __builtin_bit_cast(short8, wp1f[(kt * 8 + jt) * 64 + lane]);
      accp[0][jt] = MFMA(a, bf[0][kt], accp[0][jt]);
      accp[1][jt] = MFMA(a, bf[1][kt], accp[1][jt]);
    }
  }
#pragma unroll
  for (int m = 0; m < 2; ++m) {
    float s = 0.f;
#pragma unroll
    for (int jt = 0; jt < 8; ++jt) {
      const float4 bp = *(const float4*)(misc + 192 + jt * 16 + q * 4);
      const float4 wp = *(const float4*)(misc + 320 + jt * 16 + q * 4);
      s += fast_silu(accp[m][jt][0] + bp.x) * wp.x;
      s += fast_silu(accp[m][jt][1] + bp.y) * wp.y;
      s += fast_silu(accp[m][jt][2] + bp.z) * wp.z;
      s += fast_silu(accp[m][jt][3] + bp.w) * wp.w;
    }
    s += __shfl_xor(s, 16);
    s += __shfl_xor(s, 32);
    const int node = B0 + base + m * 16 + nn;
    if (q == 0 && node < NODES) {
      float4 o;
      o.x = pos[3 * node + 0];
      o.y = pos[3 * node + 1];
      o.z = pos[3 * node + 2];
      o.w = s + misc[448];
      *(float4*)(posw + 4 * (size_t)node) = o;
    }
  }

  // ---- folded hist (grid-stride; counts zeroed by prep); keep the rank
  const int gsz = gridDim.x * 256;
  for (int t = blockIdx.x * 256 + tid; t < EDGES; t += gsz) {
    int c = __builtin_nontemporal_load(ei + EDGES + t);
    c = (c < 0) ? 0 : ((c >= NODES) ? NODES - 1 : c);
    const int p = atomicAdd(&counts[c], 1);
    __builtin_nontemporal_store(p, ploc + t);
  }
}

#define SCB 98  // blocks of 1024: 98*1024 = 100352 >= NODES+128

__global__ __launch_bounds__(1024) void scan1_kernel(const int* __restrict__ counts,
                                                     int* __restrict__ tmp,
                                                     int* __restrict__ bsum) {
  __shared__ int part[1024];
  const int t = threadIdx.x;
  const int i = blockIdx.x * 1024 + t;
  int v = (i < NODES) ? counts[i] : 0;
  part[t] = v;
  __syncthreads();
  for (int d = 1; d < 1024; d <<= 1) {
    int u = 0;
    if (t >= d) u = part[t - d];
    __syncthreads();
    if (t >= d) part[t] += u;
    __syncthreads();
  }
  tmp[i] = part[t];  // inclusive scan within block
  if (t == 1023) bsum[blockIdx.x] = part[1023];
}

// scan2 merged in — each block re-scans the 98 block sums in LDS.
// R23: cursor gone (scatter is atomic-free); writes off only.
__global__ __launch_bounds__(1024) void scan3_kernel(const int* __restrict__ counts,
                                                     const int* __restrict__ tmp,
                                                     const int* __restrict__ bsum,
                                                     int* __restrict__ off) {
  __shared__ int sb[128];
  const int t = threadIdx.x;
  if (t < 128) sb[t] = (t < SCB) ? bsum[t] : 0;
  __syncthreads();
  for (int d = 1; d < 128; d <<= 1) {
    int u = 0;
    if (t >= d && t < 128) u = sb[t - d];
    __syncthreads();
    if (t >= d && t < 128) sb[t] += u;
    __syncthreads();
  }
  const int bx = (blockIdx.x == 0) ? 0 : sb[blockIdx.x - 1];  // exclusive
  const int i = blockIdx.x * 1024 + t;
  if (i < NODES) {
    off[i] = bx + tmp[i] - counts[i];
  } else if (i < NODES + 128) {
    off[i] = EDGES;
  }
}

// R23: atomic-free scatter — position = off[c] + p_local[e] (rank recorded
// by the hist pass). packed record: lc = c & 31, r < 2^17.
__global__ __launch_bounds__(256) void scatter_kernel(const int* __restrict__ ei,
                                                      const int* __restrict__ off,
                                                      const int* __restrict__ ploc,
                                                      unsigned int* __restrict__ srec) {
  const int t = blockIdx.x * 256 + threadIdx.x;
  if (t < EDGES) {
    int r = __builtin_nontemporal_load(ei + t);
    int c = __builtin_nontemporal_load(ei + EDGES + t);
    r = (r < 0) ? 0 : ((r >= NODES) ? NODES - 1 : r);
    c = (c < 0) ? 0 : ((c >= NODES) ? NODES - 1 : c);
    const int p = off[c] + __builtin_nontemporal_load(ploc + t);
    __builtin_nontemporal_store(((unsigned)(c & 31) << 17) | (unsigned)r, srec + p);
  }
}

// ---- main: node-centric, zero global atomics, zero in-loop barriers ----
// Frozen at the R17/R19 structure (proven 218-220 µs, spill-free):
// cols block-local in xbCol (swizzled, staged once); rows via global_load_lds
// from bf16 xb; vmcnt(1)+sched_barrier guards gload->ds_read; F/G per-m with
// h streamed to sH and 4 NAMED GEMM2 accumulators (rule #20); all in-loop
// LDS slots wave-own.
__global__ __launch_bounds__(256, 3) void node_kernel(
    const unsigned char* __restrict__ ws, float* __restrict__ out) {
  __shared__ uint4 sG[1024];                      // 16 KB row-gather frags
  __shared__ uint4 sH[1024];                      // 16 KB h frags (4 rows/wave)
  __shared__ __align__(16) float sAccX[NB * 68];  // 8.7 KB; cols 64..66 = pos
  __shared__ unsigned char xbCol[4096];           // 4 KB block col features
  __shared__ float4 sPosC[NB];                    // 512 B block col posw
  __shared__ unsigned int sRC[ET];                // 512 B packed (lc<<17|r)
  __shared__ float sW[ET];                        // 512 B
  __shared__ float sRel[ET * 3];                  // 1.5 KB
  __shared__ float sDist[ET];                     // 512 B

  const int tid = threadIdx.x;
  const int lane = tid & 63;
  const int wave = tid >> 6;
  const int q = lane >> 4;
  const int nn = lane & 15;
  const int base = blockIdx.x * NB;
  const int et0 = wave * 2;
  const int W32 = wave * 32;

  const int* off = (const int*)(ws + WS_OFF);
  const unsigned int* srec = (const unsigned int*)(ws + WS_SREC);
  const uint4* wx1f = (const uint4*)(ws + WS_WX1);
  const uint4* wx2f = (const uint4*)(ws + WS_WX2);
  const float* misc = (const float*)(ws + WS_MISC);
  const float* posw = (const float*)(ws + WS_POSW);
  const unsigned char* xb = ws + WS_XB;

  const int e0 = off[base];
  const int e1 = off[base + NB];

  // ---- block staging: xbCol (swizzled), sPosC, zero sAccX
  {
    const int row = tid >> 3;
    const int o = (tid & 7) << 4;
    const uint4 v = *(const uint4*)(xb + (size_t)(base + row) * 128 + o);
    *(uint4*)(xbCol + (row << 7) + (o ^ ((row & 7) << 4))) = v;
  }
  if (tid < NB) sPosC[tid] = *(const float4*)(posw + 4 * (size_t)(base + tid));
  for (int i = tid; i < NB * 68; i += 256) sAccX[i] = 0.f;

  // ---- prologue: tile-0 record + posw[r]
  unsigned int prec = 0;
  if (lane < 32) {
    int e = e0 + W32 + lane;
    e = e < EDGES ? e : EDGES - 1;
    prec = srec[e];
  }
  unsigned int rec0 = __shfl(prec, nn);
  unsigned int rec1 = __shfl(prec, 16 + nn);
  float4 pR = {0.f, 0.f, 0.f, 0.f};
  if (lane < 32) pR = *(const float4*)(posw + 4 * (size_t)(prec & 0x1FFFFu));
  __syncthreads();  // staging visible; also drains vmcnt (prec/pR done)

  // ---- issue tile-0 row gloads (stay in flight into iter 0)
  {
    const int ko = (lane >> 4) << 4;
#pragma unroll
    for (int mm = 0; mm < 2; ++mm) {
      const unsigned int rr = mm ? rec1 : rec0;
      const unsigned char* g0 = xb + ((size_t)(rr & 0x1FFFFu) << 7) + ko;
      gload16(g0, &sG[((et0 + mm) * 2 + 0) * 64]);
      gload16(g0 + 64, &sG[((et0 + mm) * 2 + 1) * 64]);
    }
  }

  const floatx4 fzero = {0.f, 0.f, 0.f, 0.f};

#pragma unroll 1
  for (int t0 = e0; t0 < e1; t0 += ET) {
    // ---- A: wave-own metadata -> LDS (pC from sPosC; pR prefetched)
    if (lane < 32) {
      const int j = W32 + lane;
      const float4 pc = sPosC[prec >> 17];
      const float r0 = pR.x - pc.x;
      const float r1 = pR.y - pc.y;
      const float r2 = pR.z - pc.z;
      sRC[j] = prec;
      sW[j] = pR.w;
      sRel[3 * j + 0] = r0;
      sRel[3 * j + 1] = r1;
      sRel[3 * j + 2] = r2;
      sDist[j] = r0 * r0 + r1 * r1 + r2 * r2;
    }

    // ---- B: issue next tile's srec
    unsigned int rcN = 0;
    if (lane < 32) {
      int e = t0 + ET + W32 + lane;
      e = e < EDGES ? e : EDGES - 1;
      rcN = srec[e];
    }

    // ---- C: row gloads for THIS tile landed (rcN still in flight)
    asm volatile("s_waitcnt vmcnt(1)" ::: "memory");
    __builtin_amdgcn_sched_barrier(0);

    // ---- D: GEMM1 — kt0,1 B from sG (gload rows); kt2,3 B from xbCol
    floatx4 acc1[2][8];
#pragma unroll
    for (int m = 0; m < 2; ++m)
#pragma unroll
      for (int j = 0; j < 8; ++j) acc1[m][j] = fzero;
#pragma unroll 1
    for (int kt = 0; kt < 2; ++kt) {
      const short8 b0 = __builtin_bit_cast(short8, sG[((et0 + 0) * 2 + kt) * 64 + lane]);
      const short8 b1 = __builtin_bit_cast(short8, sG[((et0 + 1) * 2 + kt) * 64 + lane]);
#pragma unroll
      for (int jt = 0; jt < 8; ++jt) {
        const short8 a = __builtin_bit_cast(short8, wx1f[(kt * 8 + jt) * 64 + lane]);
        acc1[0][jt] = MFMA(a, b0, acc1[0][jt]);
        acc1[1][jt] = MFMA(a, b1, acc1[1][jt]);
      }
    }
    {
      const int lc0 = (int)(rec0 >> 17);
      const int lc1 = (int)(rec1 >> 17);
#pragma unroll 1
      for (int kt = 2; kt < 4; ++kt) {
        const int o = ((kt & 1) << 6) | ((lane >> 4) << 4);
        const short8 b0 =
            *(const short8*)(xbCol + (lc0 << 7) + (o ^ ((lc0 & 7) << 4)));
        const short8 b1 =
            *(const short8*)(xbCol + (lc1 << 7) + (o ^ ((lc1 & 7) << 4)));
#pragma unroll
        for (int jt = 0; jt < 8; ++jt) {
          const short8 a = __builtin_bit_cast(short8, wx1f[(kt * 8 + jt) * 64 + lane]);
          acc1[0][jt] = MFMA(a, b0, acc1[0][jt]);
          acc1[1][jt] = MFMA(a, b1, acc1[1][jt]);
        }
      }
    }

    // ---- E: next-tile prefetch (sG rows free; cover = F+G)
    __builtin_amdgcn_sched_barrier(0);
    {
      if (lane < 32) pR = *(const float4*)(posw + 4 * (size_t)(rcN & 0x1FFFFu));
      const unsigned int rec0n = __shfl(rcN, nn);
      const unsigned int rec1n = __shfl(rcN, 16 + nn);
      const int ko = (lane >> 4) << 4;
#pragma unroll
      for (int mm = 0; mm < 2; ++mm) {
        const unsigned int rr = mm ? rec1n : rec0n;
        const unsigned char* g0 = xb + ((size_t)(rr & 0x1FFFFu) << 7) + ko;
        gload16(g0, &sG[((et0 + mm) * 2 + 0) * 64]);
        gload16(g0 + 64, &sG[((et0 + mm) * 2 + 1) * 64]);
      }
      rec0 = rec0n;
      rec1 = rec1n;
      prec = rcN;
    }

    // ---- F+G per m: epi1(m)->sH direct, GEMM2(m) named accs, scatter(m)
#pragma unroll
    for (int m = 0; m < 2; ++m) {
      const int el = (et0 + m) * 16 + nn;
      const float dist = sDist[el];
      // epi1(m): 8 static jt, stream h straight to sH rows wave*4+kt2
#pragma unroll
      for (int jt = 0; jt < 8; ++jt) {
        const float4 bx = *(const float4*)(misc + 0 + jt * 16 + q * 4);
        const float4 wd = *(const float4*)(misc + 456 + jt * 16 + q * 4);
        const unsigned int h01 = cvtpk2bf(fast_silu(acc1[m][jt][0] + bx.x + dist * wd.x),
                                          fast_silu(acc1[m][jt][1] + bx.y + dist * wd.y));
        const unsigned int h23 = cvtpk2bf(fast_silu(acc1[m][jt][2] + bx.z + dist * wd.z),
                                          fast_silu(acc1[m][jt][3] + bx.w + dist * wd.w));
        const int j0 = jt * 16 + q * 4;  // 0..127
        const int kt2 = j0 >> 5;
        const int lane2 = (((j0 & 31) >> 3) << 4) | nn;
        const int byteoff = (j0 & 7) << 1;
        uint2* dst = (uint2*)((char*)sH +
                              (((size_t)((wave * 4 + kt2) * 64 + lane2)) << 4) + byteoff);
        *dst = make_uint2(h01, h23);
      }
      // GEMM2(m): 4 named accumulators (16 AGPR)
      floatx4 a20 = fzero, a21 = fzero, a22 = fzero, a23 = fzero;
#pragma unroll 1
      for (int kt = 0; kt < 4; ++kt) {
        const short8 b = __builtin_bit_cast(short8, sH[(wave * 4 + kt) * 64 + lane]);
        a20 = MFMA(__builtin_bit_cast(short8, wx2f[(kt * 4 + 0) * 64 + lane]), b, a20);
        a21 = MFMA(__builtin_bit_cast(short8, wx2f[(kt * 4 + 1) * 64 + lane]), b, a21);
        a22 = MFMA(__builtin_bit_cast(short8, wx2f[(kt * 4 + 2) * 64 + lane]), b, a22);
        a23 = MFMA(__builtin_bit_cast(short8, wx2f[(kt * 4 + 3) * 64 + lane]), b, a23);
      }
      // scatter(m): masks + pos + x-features
      const bool vE = (t0 + el) < e1;
      int lcv = (int)(sRC[el] >> 17);
      if (!vE) lcv = -1 - nn;  // singleton segments for invalid lanes
      // unconditional DPPs (convergent!) then bitwise combines:
      const int k1 = dpp_i<0x111>(lcv);
      const int k2 = dpp_i<0x112>(lcv);
      const int k4 = dpp_i<0x114>(lcv);
      const int k8 = dpp_i<0x118>(lcv);
      const int kn = dpp_i<0x101>(lcv);
      const bool m1 = (nn >= 1) & (k1 == lcv);
      const bool m2 = (nn >= 2) & (k2 == lcv);
      const bool m4 = (nn >= 4) & (k4 == lcv);
      const bool m8 = (nn >= 8) & (k8 == lcv);
      const bool tail = vE & ((nn == 15) | (kn != lcv));

      // pos update (w precomputed per node)
      const float wv = sW[el];
      float p0 = segscan(wv * sRel[3 * el + 0], m1, m2, m4, m8);
      float p1 = segscan(wv * sRel[3 * el + 1], m1, m2, m4, m8);
      float p2 = segscan(wv * sRel[3 * el + 2], m1, m2, m4, m8);
      if (tail && q == 0) {
        float* ap = sAccX + lcv * 68 + 64;  // pos acc lives in the pad
        lds_add(ap + 0, p0);
        lds_add(ap + 1, p1);
        lds_add(ap + 2, p2);
      }
      {
        const float4 b2 = *(const float4*)(misc + 128 + 0 * 16 + q * 4);
        float v0 = segscan(a20[0] + b2.x, m1, m2, m4, m8);
        float v1 = segscan(a20[1] + b2.y, m1, m2, m4, m8);
        float v2 = segscan(a20[2] + b2.z, m1, m2, m4, m8);
        float v3 = segscan(a20[3] + b2.w, m1, m2, m4, m8);
        if (tail) {
          float* arow = sAccX + lcv * 68 + q * 4;
          lds_add(arow + 0, v0);
          lds_add(arow + 1, v1);
          lds_add(arow + 2, v2);
          lds_add(arow + 3, v3);
        }
      }
      {
        const float4 b2 = *(const float4*)(misc + 128 + 1 * 16 + q * 4);
        float v0 = segscan(a21[0] + b2.x, m1, m2, m4, m8);
        float v1 = segscan(a21[1] + b2.y, m1, m2, m4, m8);
        float v2 = segscan(a21[2] + b2.z, m1, m2, m4, m8);
        float v3 = segscan(a21[3] + b2.w, m1, m2, m4, m8);
        if (tail) {
          float* arow = sAccX + lcv * 68 + 16 + q * 4;
          lds_add(arow + 0, v0);
          lds_add(arow + 1, v1);
          lds_add(arow + 2, v2);
          lds_add(arow + 3, v3);
        }
      }
      {
        const float4 b2 = *(const float4*)(misc + 128 + 2 * 16 + q * 4);
        float v0 = segscan(a22[0] + b2.x, m1, m2, m4, m8);
        float v1 = segscan(a22[1] + b2.y, m1, m2, m4, m8);
        float v2 = segscan(a22[2] + b2.z, m1, m2, m4, m8);
        float v3 = segscan(a22[3] + b2.w, m1, m2, m4, m8);
        if (tail) {
          float* arow = sAccX + lcv * 68 + 32 + q * 4;
          lds_add(arow + 0, v0);
          lds_add(arow + 1, v1);
          lds_add(arow + 2, v2);
          lds_add(arow + 3, v3);
        }
      }
      {
        const float4 b2 = *(const float4*)(misc + 128 + 3 * 16 + q * 4);
        float v0 = segscan(a23[0] + b2.x, m1, m2, m4, m8);
        float v1 = segscan(a23[1] + b2.y, m1, m2, m4, m8);
        float v2 = segscan(a23[2] + b2.z, m1, m2, m4, m8);
        float v3 = segscan(a23[3] + b2.w, m1, m2, m4, m8);
        if (tail) {
          float* arow = sAccX + lcv * 68 + 48 + q * 4;
          lds_add(arow + 0, v0);
          lds_add(arow + 1, v1);
          lds_add(arow + 2, v2);
          lds_add(arow + 3, v3);
        }
      }
    }
    // no end-of-loop barrier: all in-loop LDS arrays are wave-own slots.
  }
  __syncthreads();  // all waves' LDS-atomic accumulates done

  // ---- final coalesced stores (no global atomics); NODES % NB == 0
  {
    const int n = base + (tid >> 3);
    const int c0 = (tid & 7) * 8;
    float* orow = out + (size_t)n * 64 + c0;
    const float* arow = sAccX + (tid >> 3) * 68 + c0;
    *(float4*)(orow + 0) = *(const float4*)(arow + 0);
    *(float4*)(orow + 4) = *(const float4*)(arow + 4);
    if (tid < NB * 3)
      out[(size_t)NODES * 64 + base * 3 + tid] = sAccX[(tid / 3) * 68 + 64 + (tid % 3)];
  }
}

extern "C" void kernel_launch(void* const* d_in, const int* in_sizes, int n_in,
                              void* d_out, int out_size, void* d_ws, size_t ws_size,
                              hipStream_t stream) {
  (void)in_sizes; (void)n_in; (void)ws_size; (void)out_size;
  const float* x = (const float*)d_in[0];
  const float* pos = (const float*)d_in[1];
  const int* ei = (const int*)d_in[2];
  const float* Wx1 = (const float*)d_in[3];
  const float* bx1 = (const float*)d_in[4];
  const float* Wx2 = (const float*)d_in[5];
  const float* bx2 = (const float*)d_in[6];
  const float* Wp1 = (const float*)d_in[7];
  const float* bp1 = (const float*)d_in[8];
  const float* Wp2 = (const float*)d_in[9];
  const float* bp2 = (const float*)d_in[10];
  float* out = (float*)d_out;
  unsigned char* ws = (unsigned char*)d_ws;

  int* counts = (int*)(ws + WS_CNT);
  int* off = (int*)(ws + WS_OFF);
  int* ploc = (int*)(ws + WS_PLOC);
  int* tmp = (int*)(ws + WS_TMP);      // aliased with srec (dies before scatter)
  int* bsum = (int*)(ws + WS_BSUM);
  unsigned int* srec = (unsigned int*)(ws + WS_SREC);

  prep_kernel<<<64, 256, 0, stream>>>(Wx1, Wx2, Wp1, bx1, bx2, bp1, Wp2, bp2, ws);
  wpos_kernel<<<NBW, 256, 0, stream>>>(x, pos, ei, ws);  // + folded hist (keeps rank)
  scan1_kernel<<<SCB, 1024, 0, stream>>>(counts, tmp, bsum);
  scan3_kernel<<<SCB, 1024, 0, stream>>>(counts, tmp, bsum, off);
  const int eb = (EDGES + 255) / 256;
  scatter_kernel<<<eb, 256, 0, stream>>>(ei, off, ploc, srec);
  node_kernel<<<NBLK, 256, 0, stream>>>(ws, out);
}